// Round 12
// baseline (1889.091 us; speedup 1.0000x reference)
//
#include <hip/hip_runtime.h>
#include <hip/hip_bf16.h>

namespace {

constexpr int B_  = 128;
constexpr int TL  = 50, CL = 200, NNODE = 250;
constexpr int H_  = 256, D_ = 512;
constexpr long NODE_ELE = 128L * 250 * 512;   // per side

typedef __attribute__((ext_vector_type(8))) short bf16x8;
typedef __attribute__((ext_vector_type(4))) float f32x4;

__device__ inline float bits2f(unsigned v) { union { unsigned u; float f; } c; c.u = v; return c.f; }
__device__ inline unsigned f2bits(float x) { union { float f; unsigned u; } c; c.f = x; return c.u; }
__device__ inline unsigned short bfbits(float x) {
  __hip_bfloat16 b = __float2bfloat16(x);
  return *(unsigned short*)&b;
}
__device__ inline float bfsel(uint2 v, int r) {        // r-th bf16 of a 4-pack
  unsigned w = (r < 2) ? v.x : v.y;
  return bits2f((r & 1) ? (w & 0xFFFF0000u) : (w << 16));
}
__device__ inline float sigf(float x)  { return 1.f / (1.f + __expf(-x)); }
__device__ inline float tanhf_(float x){ return 1.f - 2.f / (__expf(2.f * x) + 1.f); }

// =============== bf16 MFMA GEMM: C[z] = A[za] @ B[z]^T (B is [N][K]) ==========
// za = z >> zShiftA (per-side weights at zShiftA=7). OUT modes:
// 0: f32 out. 1: +bias -> bf16. 3: bf16 out, zero-fill cols [N,256).
// 5: +bf16 Res, relu -> bf16 out.
struct BGemmArgs {
  const __hip_bfloat16* A; const __hip_bfloat16* B;
  const int* idx; const float* bias; const __hip_bfloat16* Res;
  void* C;
  long aStride, bStride, biasStride, cStride, rStride;
  int M, N, Kreal, lda, ldb, ldc, zShiftA;
};

template<bool GATHER, int OUT>
__global__ __launch_bounds__(256) void bgemm_k(BGemmArgs g) {
  __shared__ __align__(16) __hip_bfloat16 As[128 * 64];   // [r][k] XOR-swizzled
  __shared__ __align__(16) __hip_bfloat16 Bs[128 * 64];
  const int z = blockIdx.z;
  const int m0 = blockIdx.x * 128, n0 = blockIdx.y * 128;
  const int tid = threadIdx.x;
  const int lane = tid & 63, wv = tid >> 6;
  const int wr = wv >> 1, wc = wv & 1;                    // wave -> 64x64 quadrant
  const __hip_bfloat16* Ab = GATHER ? g.A : g.A + (long)(z >> g.zShiftA) * g.aStride;
  const __hip_bfloat16* Bb = g.B + (long)z * g.bStride;
  const int sr = tid >> 3, so = tid & 7;                  // staging: row, col-octet
  f32x4 acc[4][4];
  #pragma unroll
  for (int i = 0; i < 4; ++i)
    #pragma unroll
    for (int j = 0; j < 4; ++j) acc[i][j] = (f32x4){0.f, 0.f, 0.f, 0.f};

  const int ktiles = (g.Kreal + 63) >> 6;
  for (int kt = 0; kt < ktiles; ++kt) {
    const int k0 = kt * 64;
    __syncthreads();
    #pragma unroll
    for (int p = 0; p < 4; ++p) {           // A tile 128x64
      int r = p * 32 + sr;
      int row = m0 + r;
      int kg = k0 + so * 8;
      uint4 v = make_uint4(0, 0, 0, 0);
      if (row < g.M && kg + 8 <= g.Kreal) {
        long ao = GATHER ? (long)g.idx[row] * g.lda : (long)row * g.lda;
        v = *(const uint4*)(Ab + ao + kg);
      }
      *(uint4*)((char*)As + ((r * 128 + so * 16) ^ ((r & 7) << 4))) = v;
    }
    #pragma unroll
    for (int p = 0; p < 4; ++p) {           // B tile 128x64 (rows = n)
      int r = p * 32 + sr;
      int row = n0 + r;
      int kg = k0 + so * 8;
      uint4 v = make_uint4(0, 0, 0, 0);
      if (row < g.N && kg + 8 <= g.Kreal)
        v = *(const uint4*)(Bb + (long)row * g.ldb + kg);
      *(uint4*)((char*)Bs + ((r * 128 + so * 16) ^ ((r & 7) << 4))) = v;
    }
    __syncthreads();
    #pragma unroll
    for (int ks = 0; ks < 2; ++ks) {
      bf16x8 af[4], bfr[4];
      #pragma unroll
      for (int i = 0; i < 4; ++i) {
        int ra = wr * 64 + i * 16 + (lane & 15);
        af[i] = *(const bf16x8*)((const char*)As +
                 ((ra * 128 + ks * 64 + (lane >> 4) * 16) ^ ((ra & 7) << 4)));
        int rb = wc * 64 + i * 16 + (lane & 15);
        bfr[i] = *(const bf16x8*)((const char*)Bs +
                 ((rb * 128 + ks * 64 + (lane >> 4) * 16) ^ ((rb & 7) << 4)));
      }
      #pragma unroll
      for (int i = 0; i < 4; ++i)
        #pragma unroll
        for (int j = 0; j < 4; ++j)
          acc[i][j] = __builtin_amdgcn_mfma_f32_16x16x32_bf16(af[i], bfr[j], acc[i][j], 0, 0, 0);
    }
  }
  // ---- epilogue: D col = lane&15 (n), row = (lane>>4)*4 + r (m) ----
  const long cz = (long)z * g.cStride;
  #pragma unroll
  for (int i = 0; i < 4; ++i) {
    int rbase = m0 + wr * 64 + i * 16 + ((lane >> 4) << 2);
    #pragma unroll
    for (int j = 0; j < 4; ++j) {
      int col = n0 + wc * 64 + j * 16 + (lane & 15);
      #pragma unroll
      for (int r = 0; r < 4; ++r) {
        int row = rbase + r;
        float v = acc[i][j][r];
        if (OUT == 0) {
          if (row < g.M && col < g.N)
            ((float*)g.C)[cz + (long)row * g.ldc + col] = v;
        } else if (OUT == 1) {
          if (row < g.M && col < g.N) {
            v += g.bias[(long)z * g.biasStride + col];
            ((__hip_bfloat16*)g.C)[cz + (long)row * g.ldc + col] = __float2bfloat16(v);
          }
        } else if (OUT == 3) {
          if (row < g.M)
            ((__hip_bfloat16*)g.C)[cz + (long)row * g.ldc + col] =
                __float2bfloat16(col < g.N ? v : 0.f);
        } else {  // OUT == 5: +bf16 res, relu, bf16 out
          if (row < g.M && col < g.N) {
            v += __bfloat162float(g.Res[(long)z * g.rStride + (long)row * g.ldc + col]);
            v = fmaxf(v, 0.f);
            ((__hip_bfloat16*)g.C)[cz + (long)row * g.ldc + col] = __float2bfloat16(v);
          }
        }
      }
    }
  }
}

// ---------------- fused prep: whh/gcnW/emb/wih -> bf16(+pad), biasC ----------
struct PrepArgs {
  const float* whh[4];    // tgt, tgc, sgt, sgc (each [2][768][256])
  const float* gcnW[2];   // task, shared (each [2][512][512])
  const float* emb;       // [30000][300]
  const float* wih[4];    // each [2][768][300]
  const float* bih[4];
  const float* bhh[4];
  __hip_bfloat16 *whhbf, *gcnWbf, *embbf;
  __hip_bfloat16* wihbf[4];
  float* biasC;           // [4][2][768]
};

constexpr long PR0 = 1572864;            // whh
constexpr long PR1 = PR0 + 1048576;      // gcnW
constexpr long PR2 = PR1 + 9120000;      // emb pad 304
constexpr long PR3 = PR2 + 1867776;      // wih pad 304 (4x 466944)
constexpr long PR4 = PR3 + 6144;         // biasC

__global__ __launch_bounds__(256) void prep_k(PrepArgs a) {
  long i = (long)blockIdx.x * 256 + threadIdx.x;
  if (i >= PR4) return;
  if (i < PR0) {
    int zz = (int)(i / 196608);
    long rem = i - (long)zz * 196608;
    a.whhbf[i] = __float2bfloat16(a.whh[zz >> 1][(long)(zz & 1) * 196608 + rem]);
  } else if (i < PR1) {
    long j = i - PR0;
    a.gcnWbf[j] = __float2bfloat16(a.gcnW[j / 524288][j % 524288]);
  } else if (i < PR2) {
    long j = i - PR1;
    long r = j / 304;
    int c = (int)(j - r * 304);
    a.embbf[j] = __float2bfloat16(c < 300 ? a.emb[r * 300 + c] : 0.f);
  } else if (i < PR3) {
    long j = i - PR2;
    int w = (int)(j / 466944);
    long k = j - (long)w * 466944;
    long r = k / 304;
    int c = (int)(k - r * 304);
    a.wihbf[w][k] = __float2bfloat16(c < 300 ? a.wih[w][r * 300 + c] : 0.f);
  } else {
    long j = i - PR3;
    int w = (int)(j / 1536);
    int k = (int)(j - (long)w * 1536);
    a.biasC[(long)w * 1536 + k] = a.bih[w][k] + ((k % 768) < 512 ? a.bhh[w][k] : 0.f);
  }
}

// ---------------- GRU recurrence: MFMA persistent-RNN, ALL 8 chains ----------
// grid (8,1,8): z = side*4 + sq*2 + dir; blockIdx.x = 16-batch group (64 blocks).
// 1024 threads = 16 waves = 4 waves/SIMD (vs 2 before): doubles the independent
// instruction streams so MFMA / trans / VALU / LDS pipes overlap. Wave wv owns
// 16 h-units (3 gate tiles, 24 MFMA/step; Af = 96 VGPR). h in f32 regs; bf16 h
// mirror in swizzled LDS. gi via register prefetch (one step ahead).
struct RecArgs {
  const __hip_bfloat16* whhbf;    // [8][768][256], z = side*4+sq*2+dir
  const __hip_bfloat16* gi[4];    // {task_t, task_c, shared_t, shared_c}
  const float* bhh[4];
  __hip_bfloat16* nodebf;         // [2][128][250][512]
};

__global__ __launch_bounds__(1024) void gru_rec_k(RecArgs a) {
  __shared__ __align__(16) char hbuf[2][8192];   // [buf][batch16][k256] bf16, swz
  __shared__ __align__(16) float bnS[256];       // bhh_n
  const int z = blockIdx.z;
  const int side = z >> 2, sq = (z >> 1) & 1, dir = z & 1;
  const int gidx = side * 2 + sq;
  const int T = sq ? CL : TL;
  const int toff = sq ? TL : 0;
  const __hip_bfloat16* gi = a.gi[gidx] + (long)dir * B_ * T * 768;
  const float* bhh = a.bhh[gidx] + dir * 768;
  const __hip_bfloat16* whh = a.whhbf + (long)z * 768 * 256;
  __hip_bfloat16* nodeb = a.nodebf + (long)side * NODE_ELE;
  const int b0 = blockIdx.x * 16;
  const int tid = threadIdx.x;
  const int lane = tid & 63, wv = tid >> 6;      // wv 0..15
  const int bcol = lane & 15, g4 = lane >> 4;
  const int u0 = wv * 16 + g4 * 4;               // this thread's 4 units
  const int swzh = (bcol & 15) << 4;             // bijective within 512B h-row

  // ---- A-fragments: 3 gate tiles x 8 k-slices = 96 VGPR ----
  bf16x8 Af[3][8];
  #pragma unroll
  for (int g = 0; g < 3; ++g)
    #pragma unroll
    for (int kt = 0; kt < 8; ++kt) {
      int row = g * 256 + wv * 16 + bcol;
      int col = kt * 32 + g4 * 8;
      Af[g][kt] = *(const bf16x8*)(whh + (long)row * 256 + col);
    }
  *(uint2*)&hbuf[0][tid * 8] = make_uint2(0, 0);
  if (tid < 256) bnS[tid] = bhh[512 + tid];
  __syncthreads();

  const __hip_bfloat16* gip = gi + ((long)(b0 + bcol) * T + (dir ? T - 1 : 0)) * 768 + u0;
  __hip_bfloat16* np = nodeb + ((long)(b0 + bcol) * NNODE + toff + (dir ? T - 1 : 0)) * D_
                       + dir * H_ + u0;
  const long gistep = dir ? -768L : 768L;
  const long nstep  = dir ? -(long)D_ : (long)D_;
  int cur = 0;

  float hreg[4];
  #pragma unroll
  for (int r = 0; r < 4; ++r) hreg[r] = 0.f;

  // gi preload for t=0 (4 units per gate)
  uint2 gv[3];
  #pragma unroll
  for (int g = 0; g < 3; ++g) gv[g] = *(const uint2*)(gip + g * 256);

  for (int t = 0; t < T; ++t) {
    // ---- MFMA: 3 gates x (16 units x 16 batch), bf16 h ----
    const char* hib = &hbuf[cur][0];
    f32x4 c[3];
    #pragma unroll
    for (int g = 0; g < 3; ++g) c[g] = (f32x4){0.f, 0.f, 0.f, 0.f};
    const int rb = bcol * 512 + g4 * 16;
    #pragma unroll
    for (int kt = 0; kt < 8; ++kt) {
      bf16x8 bh = *(const bf16x8*)(hib + ((rb + kt * 64) ^ swzh));
      #pragma unroll
      for (int g = 0; g < 3; ++g)
        c[g] = __builtin_amdgcn_mfma_f32_16x16x32_bf16(Af[g][kt], bh, c[g], 0, 0, 0);
    }

    // ---- activation (h_old exact in regs; r,z bias pre-folded into gi) ----
    float4 bn = *(const float4*)&bnS[u0];
    #pragma unroll
    for (int r = 0; r < 4; ++r) {
      float bnv = (r == 0) ? bn.x : (r == 1) ? bn.y : (r == 2) ? bn.z : bn.w;
      float rr = sigf(bfsel(gv[0], r) + c[0][r]);
      float zz = sigf(bfsel(gv[1], r) + c[1][r]);
      float nn = tanhf_(bfsel(gv[2], r) + rr * (c[2][r] + bnv));
      hreg[r] = (1.f - zz) * nn + zz * hreg[r];
    }

    // ---- issue gi loads for t+1 (in flight across pack+barrier+next MFMA) ----
    {
      const __hip_bfloat16* gn = (t + 1 < T) ? gip + gistep : gip;
      gip = gn;
      #pragma unroll
      for (int g = 0; g < 3; ++g) gv[g] = *(const uint2*)(gn + g * 256);
    }

    // ---- pack h -> bf16 (round-half-up); store to node + next h-buffer ----
    unsigned hb[4];
    #pragma unroll
    for (int r = 0; r < 4; ++r)
      hb[r] = (f2bits(hreg[r]) + 0x8000u) & 0xFFFF0000u;
    uint2 hiw;
    hiw.x = (hb[0] >> 16) | hb[1];
    hiw.y = (hb[2] >> 16) | hb[3];
    *(uint2*)np = hiw;                                       // node (fire-and-forget)
    *(uint2*)(&hbuf[cur ^ 1][0] + ((bcol * 512 + u0 * 2) ^ swzh)) = hiw;
    np += nstep;
    asm volatile("s_waitcnt lgkmcnt(0)" ::: "memory");
    __builtin_amdgcn_sched_barrier(0);
    __builtin_amdgcn_s_barrier();
    cur ^= 1;
  }
}

// ---------------- attention over claims (bf16 node, both sides) ----------------
__global__ __launch_bounds__(256) void attn_k(const __hip_bfloat16* nodeAll,
                                              float* wT, float* wS) {
  int b = blockIdx.x, side = blockIdx.y;
  const __hip_bfloat16* node = nodeAll + (long)side * NODE_ELE;
  float* w = side ? wS : wT;
  __shared__ float tl[512];
  __shared__ float sc[CL];
  int tid = threadIdx.x;
  {
    const __hip_bfloat16* tr = node + ((long)b * NNODE + (TL - 1)) * D_;
    tl[tid]       = __bfloat162float(tr[tid]);
    tl[tid + 256] = __bfloat162float(tr[tid + 256]);
  }
  __syncthreads();
  int wid = tid >> 6, lane = tid & 63;
  for (int c = wid; c < CL; c += 4) {
    const __hip_bfloat16* row = node + ((long)b * NNODE + TL + c) * D_;
    uint4 v = *(const uint4*)(row + lane * 8);
    const float* tp = &tl[lane * 8];
    float acc = bits2f(v.x << 16)         * tp[0] + bits2f(v.x & 0xFFFF0000u) * tp[1]
              + bits2f(v.y << 16)         * tp[2] + bits2f(v.y & 0xFFFF0000u) * tp[3]
              + bits2f(v.z << 16)         * tp[4] + bits2f(v.z & 0xFFFF0000u) * tp[5]
              + bits2f(v.w << 16)         * tp[6] + bits2f(v.w & 0xFFFF0000u) * tp[7];
    #pragma unroll
    for (int o = 32; o; o >>= 1) acc += __shfl_xor(acc, o, 64);
    if (lane == 0) sc[c] = acc;
  }
  __syncthreads();
  if (wid == 0) {
    float v[4]; float m = -1e30f;
    #pragma unroll
    for (int i = 0; i < 4; ++i) {
      int c = lane + 64 * i;
      v[i] = (c < CL) ? sc[c] : -1e30f;
      m = fmaxf(m, v[i]);
    }
    #pragma unroll
    for (int o = 32; o; o >>= 1) m = fmaxf(m, __shfl_xor(m, o, 64));
    float s = 0.f;
    #pragma unroll
    for (int i = 0; i < 4; ++i) {
      int c = lane + 64 * i;
      v[i] = (c < CL) ? expf(v[i] - m) : 0.f;
      s += v[i];
    }
    #pragma unroll
    for (int o = 32; o; o >>= 1) s += __shfl_xor(s, o, 64);
    float inv = 1.f / s;
    #pragma unroll
    for (int i = 0; i < 4; ++i) {
      int c = lane + 64 * i;
      if (c < CL) w[(long)b * CL + c] = v[i] * inv;
    }
  }
}

// ---------------- row softmax: f32 in (ld 256, len 250) -> bf16 out, 0-pad ----
__global__ __launch_bounds__(256) void softmaxbf_k(const float* in, __hip_bfloat16* out) {
  int row = blockIdx.x * 4 + (threadIdx.x >> 6);
  int lane = threadIdx.x & 63;
  const float* p = in + (long)row * 256;
  __hip_bfloat16* q = out + (long)row * 256;
  float v[4]; float m = -1e30f;
  #pragma unroll
  for (int i = 0; i < 4; ++i) {
    int c = lane + i * 64;
    v[i] = (c < 250) ? p[c] : -1e30f;
    m = fmaxf(m, v[i]);
  }
  #pragma unroll
  for (int o = 32; o; o >>= 1) m = fmaxf(m, __shfl_xor(m, o, 64));
  float s = 0.f;
  #pragma unroll
  for (int i = 0; i < 4; ++i) {
    int c = lane + i * 64;
    if (c < 250) { v[i] = __expf(v[i] - m); s += v[i]; }
  }
  #pragma unroll
  for (int o = 32; o; o >>= 1) s += __shfl_xor(s, o, 64);
  float inv = 1.f / s;
  #pragma unroll
  for (int i = 0; i < 4; ++i) {
    int c = lane + i * 64;
    q[c] = __float2bfloat16((c < 250) ? v[i] * inv : 0.f);
  }
}

// ---------------- weighted claim pooling (bf16 node, both sides) ----------------
__global__ __launch_bounds__(256) void rep_k(const __hip_bfloat16* nodeAll,
                                             const float* wT, const float* wS,
                                             float* rep) {
  int b = blockIdx.x, side = blockIdx.y;
  const __hip_bfloat16* node = nodeAll + (long)side * NODE_ELE;
  const float* w = side ? wS : wT;
  __shared__ float wl[CL];
  int tid = threadIdx.x;
  if (tid < CL) wl[tid] = w[(long)b * CL + tid];
  __syncthreads();
  #pragma unroll
  for (int h = 0; h < 2; ++h) {
    int d = tid + h * 256;
    float acc = 0.f;
    for (int c = 0; c < CL; ++c)
      acc = fmaf(wl[c], __bfloat162float(node[((long)b * NNODE + TL + c) * D_ + d]), acc);
    rep[((long)side * B_ + b) * D_ + d] = acc;
  }
}

// ---------------- final linear ----------------
__global__ __launch_bounds__(256) void final_k(const float* rep, const float* linW,
                                               const float* linb, float* out) {
  int b = blockIdx.x, tid = threadIdx.x;
  float a0 = 0.f, a1 = 0.f, a2 = 0.f;
  for (int d = tid; d < 1024; d += 256) {
    float x = rep[(long)(d >> 9) * (B_ * D_) + (long)b * D_ + (d & 511)];
    a0 = fmaf(x, linW[d], a0);
    a1 = fmaf(x, linW[1024 + d], a1);
    a2 = fmaf(x, linW[2048 + d], a2);
  }
  #pragma unroll
  for (int o = 32; o; o >>= 1) {
    a0 += __shfl_xor(a0, o, 64);
    a1 += __shfl_xor(a1, o, 64);
    a2 += __shfl_xor(a2, o, 64);
  }
  __shared__ float red[3][4];
  int wid = tid >> 6, lane = tid & 63;
  if (lane == 0) { red[0][wid] = a0; red[1][wid] = a1; red[2][wid] = a2; }
  __syncthreads();
  if (tid == 0) {
    out[b * 3 + 0] = red[0][0] + red[0][1] + red[0][2] + red[0][3] + linb[0];
    out[b * 3 + 1] = red[1][0] + red[1][1] + red[1][2] + red[1][3] + linb[1];
    out[b * 3 + 2] = red[2][0] + red[2][1] + red[2][2] + red[2][3] + linb[2];
  }
}

// ---------------- diagnostic ----------------
__global__ void diag_k(float* out, int n, float v) {
  int i = blockIdx.x * blockDim.x + threadIdx.x;
  if (i < n) out[i] = v;
}

} // namespace

extern "C" void kernel_launch(void* const* d_in, const int* in_sizes, int n_in,
                              void* d_out, int out_size, void* d_ws, size_t ws_size,
                              hipStream_t stream) {
  const int* task_target   = (const int*)d_in[1];
  const int* shared_target = (const int*)d_in[2];
  const int* task_claim    = (const int*)d_in[3];
  const int* shared_claim  = (const int*)d_in[4];
  const float* emb      = (const float*)d_in[9];
  const float* tgt_wih  = (const float*)d_in[10];
  const float* tgt_whh  = (const float*)d_in[11];
  const float* tgt_bih  = (const float*)d_in[12];
  const float* tgt_bhh  = (const float*)d_in[13];
  const float* tgc_wih  = (const float*)d_in[14];
  const float* tgc_whh  = (const float*)d_in[15];
  const float* tgc_bih  = (const float*)d_in[16];
  const float* tgc_bhh  = (const float*)d_in[17];
  const float* sgt_wih  = (const float*)d_in[18];
  const float* sgt_whh  = (const float*)d_in[19];
  const float* sgt_bih  = (const float*)d_in[20];
  const float* sgt_bhh  = (const float*)d_in[21];
  const float* sgc_wih  = (const float*)d_in[22];
  const float* sgc_whh  = (const float*)d_in[23];
  const float* sgc_bih  = (const float*)d_in[24];
  const float* sgc_bhh  = (const float*)d_in[25];
  const float* gcnW_task   = (const float*)d_in[26];
  const float* gcnW_shared = (const float*)d_in[27];
  const float* linW = (const float*)d_in[28];
  const float* linb = (const float*)d_in[29];
  float* out = (float*)d_out;

  // ---- workspace plan (bytes); total ~268.1 MB <= 256 MiB ----
  const size_t SZ_WHH   = 3145728;
  const size_t SZ_GCNW  = 2097152;
  const size_t SZ_BIASC = 24576;
  const size_t SZ_ARENA = 196608000;    // gi all 4 (phase A) / GCN scratch (phase B)
  const size_t SZ_NODE  = 65536000;     // 2 sides x 128x250x512 bf16
  const size_t SZ_W     = 102400;
  const size_t SZ_REP   = 524288;
  const size_t NEED = SZ_WHH + SZ_GCNW + SZ_BIASC + SZ_ARENA + SZ_NODE
                      + 2 * SZ_W + SZ_REP + 4096;

  if (ws_size < NEED) {
    diag_k<<<(out_size + 255) / 256, 256, 0, stream>>>(out, out_size,
                                                       (float)(ws_size >> 20));
    return;
  }

  char* p = (char*)d_ws;
  auto alloc = [&](size_t bytes) { char* r = p; p += (bytes + 255) & ~(size_t)255; return r; };
  __hip_bfloat16* whhbf  = (__hip_bfloat16*)alloc(SZ_WHH);
  __hip_bfloat16* gcnWbf = (__hip_bfloat16*)alloc(SZ_GCNW);   // [side][layer][512][512]
  float* biasC = (float*)alloc(SZ_BIASC);                     // [4][2][768]
  char* arena  = alloc(SZ_ARENA);
  char* nodeC  = alloc(SZ_NODE);
  float* wT    = (float*)alloc(SZ_W);
  float* wS    = (float*)alloc(SZ_W);
  float* rep   = (float*)alloc(SZ_REP);
  __hip_bfloat16* nodebf = (__hip_bfloat16*)nodeC;

  // phase-A views: gi for all 4 GRUs in arena; emb/wih conversions alias nodebf
  __hip_bfloat16* gi_tt = (__hip_bfloat16*)(arena);
  __hip_bfloat16* gi_tc = (__hip_bfloat16*)(arena + 19660800);
  __hip_bfloat16* gi_st = (__hip_bfloat16*)(arena + 98304000);
  __hip_bfloat16* gi_sc = (__hip_bfloat16*)(arena + 117964800);
  __hip_bfloat16* embbf = (__hip_bfloat16*)(nodeC);                  // [30000][304]
  __hip_bfloat16* wihbf[4] = {                                       // [2][768][304] each
    (__hip_bfloat16*)(nodeC + 18240000),
    (__hip_bfloat16*)(nodeC + 19173888),
    (__hip_bfloat16*)(nodeC + 20107776),
    (__hip_bfloat16*)(nodeC + 21041664)};
  // phase-B (GCN) views of arena, both sides fused (z = 0..255)
  __hip_bfloat16* tmpbf  = (__hip_bfloat16*)(arena);                 // [256][250][512]
  __hip_bfloat16* corrbf = (__hip_bfloat16*)(arena + 65536000);      // [256][250][256]
  float*          corrF  = (float*)(arena + 98304000);               // [256][250][256] f32
  __hip_bfloat16* transT = (__hip_bfloat16*)(arena + 98304000);      // aliases corrF (dead)

  // ---- fused prep (1 dispatch) ----
  {
    PrepArgs pa;
    pa.whh[0] = tgt_whh; pa.whh[1] = tgc_whh; pa.whh[2] = sgt_whh; pa.whh[3] = sgc_whh;
    pa.gcnW[0] = gcnW_task; pa.gcnW[1] = gcnW_shared;
    pa.emb = emb;
    pa.wih[0] = tgt_wih; pa.wih[1] = tgc_wih; pa.wih[2] = sgt_wih; pa.wih[3] = sgc_wih;
    pa.bih[0] = tgt_bih; pa.bih[1] = tgc_bih; pa.bih[2] = sgt_bih; pa.bih[3] = sgc_bih;
    pa.bhh[0] = tgt_bhh; pa.bhh[1] = tgc_bhh; pa.bhh[2] = sgt_bhh; pa.bhh[3] = sgc_bhh;
    pa.whhbf = whhbf; pa.gcnWbf = gcnWbf; pa.embbf = embbf;
    pa.wihbf[0] = wihbf[0]; pa.wihbf[1] = wihbf[1];
    pa.wihbf[2] = wihbf[2]; pa.wihbf[3] = wihbf[3];
    pa.biasC = biasC;
    prep_k<<<(int)((PR4 + 255) / 256), 256, 0, stream>>>(pa);
  }

  // ---- projections: gi = emb[tok] @ Wih^T + biasC (bf16) ----
  auto proj = [&](const int* idx, __hip_bfloat16* wih, const float* bias,
                  __hip_bfloat16* gi, int Mrows, int gx) {
    BGemmArgs ga{};
    ga.A = embbf; ga.idx = idx; ga.B = wih; ga.bias = bias; ga.C = gi;
    ga.aStride = 0; ga.bStride = 768L * 304; ga.biasStride = 768;
    ga.cStride = (long)Mrows * 768; ga.zShiftA = 0;
    ga.M = Mrows; ga.N = 768; ga.Kreal = 304; ga.lda = 304; ga.ldb = 304; ga.ldc = 768;
    bgemm_k<true, 1><<<dim3(gx, 6, 2), 256, 0, stream>>>(ga);
  };
  proj(task_target,   wihbf[0], biasC,        gi_tt, 6400, 50);
  proj(task_claim,    wihbf[1], biasC + 1536, gi_tc, 25600, 200);
  proj(shared_target, wihbf[2], biasC + 3072, gi_st, 6400, 50);
  proj(shared_claim,  wihbf[3], biasC + 4608, gi_sc, 25600, 200);

  // ---- all 8 GRU chains in ONE dispatch (writes nodebf over emb/wih alias) ----
  RecArgs ra;
  ra.whhbf = whhbf;
  ra.gi[0] = gi_tt; ra.gi[1] = gi_tc; ra.gi[2] = gi_st; ra.gi[3] = gi_sc;
  ra.bhh[0] = tgt_bhh; ra.bhh[1] = tgc_bhh; ra.bhh[2] = sgt_bhh; ra.bhh[3] = sgc_bhh;
  ra.nodebf = nodebf;
  gru_rec_k<<<dim3(8, 1, 8), 1024, 0, stream>>>(ra);

  // ---- stance attention, both sides ----
  attn_k<<<dim3(128, 2), 256, 0, stream>>>(nodebf, wT, wS);

  // ---- GCN 2 layers, BOTH sides fused (z = 0..255; side = z>>7) ----
  for (int layer = 0; layer < 2; ++layer) {
    const __hip_bfloat16* inbf = layer ? tmpbf : nodebf;   // z-contiguous across sides
    BGemmArgs ca{};   // corr = in @ in^T (f32)
    ca.A = inbf; ca.B = inbf; ca.C = corrF;
    ca.aStride = 128000; ca.bStride = 128000; ca.cStride = 64000; ca.zShiftA = 0;
    ca.M = 250; ca.N = 250; ca.Kreal = 512; ca.lda = 512; ca.ldb = 512; ca.ldc = 256;
    bgemm_k<false, 0><<<dim3(2, 2, 256), 256, 0, stream>>>(ca);
    softmaxbf_k<<<16000, 256, 0, stream>>>(corrF, corrbf);
    BGemmArgs ta{};   // trans^T = W[side] @ in^T (bf16, 0-pad cols 250..255)
    ta.A = gcnWbf + (long)layer * 262144; ta.B = inbf; ta.C = transT;
    ta.aStride = 524288; ta.bStride = 128000; ta.cStride = 131072; ta.zShiftA = 7;
    ta.M = 512; ta.N = 250; ta.Kreal = 512; ta.lda = 512; ta.ldb = 512; ta.ldc = 256;
    bgemm_k<false, 3><<<dim3(4, 2, 256), 256, 0, stream>>>(ta);
    BGemmArgs aa{};   // out = relu(res + corr @ trans), all bf16
    aa.A = corrbf; aa.B = transT; aa.Res = inbf;
    aa.C = layer ? (void*)nodebf : (void*)tmpbf;
    aa.aStride = 64000; aa.bStride = 131072; aa.cStride = 128000;
    aa.rStride = 128000; aa.zShiftA = 0;
    aa.M = 250; aa.N = 512; aa.Kreal = 256; aa.lda = 256; aa.ldb = 256; aa.ldc = 512;
    bgemm_k<false, 5><<<dim3(2, 4, 256), 256, 0, stream>>>(aa);
  }

  // ---- pooling (post-GCN node in nodebf), final linear ----
  rep_k<<<dim3(128, 2), 256, 0, stream>>>(nodebf, wT, wS, rep);
  final_k<<<dim3(128), 256, 0, stream>>>(rep, linW, linb, out);
}

// Round 13
// 1659.738 us; speedup vs baseline: 1.1382x; 1.1382x over previous
//
#include <hip/hip_runtime.h>
#include <hip/hip_bf16.h>

namespace {

constexpr int B_  = 128;
constexpr int TL  = 50, CL = 200, NNODE = 250;
constexpr int H_  = 256, D_ = 512;
constexpr long NODE_ELE = 128L * 250 * 512;   // per side

typedef __attribute__((ext_vector_type(8))) short bf16x8;
typedef __attribute__((ext_vector_type(4))) float f32x4;

__device__ inline float bits2f(unsigned v) { union { unsigned u; float f; } c; c.u = v; return c.f; }
__device__ inline unsigned f2bits(float x) { union { float f; unsigned u; } c; c.f = x; return c.u; }
__device__ inline unsigned short bfbits(float x) {
  __hip_bfloat16 b = __float2bfloat16(x);
  return *(unsigned short*)&b;
}
__device__ inline float bfsel(uint2 v, int r) {        // r-th bf16 of a 4-pack
  unsigned w = (r < 2) ? v.x : v.y;
  return bits2f((r & 1) ? (w & 0xFFFF0000u) : (w << 16));
}
__device__ inline float sigf(float x)  { return 1.f / (1.f + __expf(-x)); }
__device__ inline float tanhf_(float x){ return 1.f - 2.f / (__expf(2.f * x) + 1.f); }

// =============== bf16 MFMA GEMM: C[z] = A[za] @ B[z]^T (B is [N][K]) ==========
// za = z >> zShiftA (per-side weights at zShiftA=7). OUT modes:
// 0: f32 out. 1: +bias -> bf16. 3: bf16 out, zero-fill cols [N,256).
// 5: +bf16 Res, relu -> bf16 out.
struct BGemmArgs {
  const __hip_bfloat16* A; const __hip_bfloat16* B;
  const int* idx; const float* bias; const __hip_bfloat16* Res;
  void* C;
  long aStride, bStride, biasStride, cStride, rStride;
  int M, N, Kreal, lda, ldb, ldc, zShiftA;
};

template<bool GATHER, int OUT>
__global__ __launch_bounds__(256) void bgemm_k(BGemmArgs g) {
  __shared__ __align__(16) __hip_bfloat16 As[128 * 64];   // [r][k] XOR-swizzled
  __shared__ __align__(16) __hip_bfloat16 Bs[128 * 64];
  const int z = blockIdx.z;
  const int m0 = blockIdx.x * 128, n0 = blockIdx.y * 128;
  const int tid = threadIdx.x;
  const int lane = tid & 63, wv = tid >> 6;
  const int wr = wv >> 1, wc = wv & 1;                    // wave -> 64x64 quadrant
  const __hip_bfloat16* Ab = GATHER ? g.A : g.A + (long)(z >> g.zShiftA) * g.aStride;
  const __hip_bfloat16* Bb = g.B + (long)z * g.bStride;
  const int sr = tid >> 3, so = tid & 7;                  // staging: row, col-octet
  f32x4 acc[4][4];
  #pragma unroll
  for (int i = 0; i < 4; ++i)
    #pragma unroll
    for (int j = 0; j < 4; ++j) acc[i][j] = (f32x4){0.f, 0.f, 0.f, 0.f};

  const int ktiles = (g.Kreal + 63) >> 6;
  for (int kt = 0; kt < ktiles; ++kt) {
    const int k0 = kt * 64;
    __syncthreads();
    #pragma unroll
    for (int p = 0; p < 4; ++p) {           // A tile 128x64
      int r = p * 32 + sr;
      int row = m0 + r;
      int kg = k0 + so * 8;
      uint4 v = make_uint4(0, 0, 0, 0);
      if (row < g.M && kg + 8 <= g.Kreal) {
        long ao = GATHER ? (long)g.idx[row] * g.lda : (long)row * g.lda;
        v = *(const uint4*)(Ab + ao + kg);
      }
      *(uint4*)((char*)As + ((r * 128 + so * 16) ^ ((r & 7) << 4))) = v;
    }
    #pragma unroll
    for (int p = 0; p < 4; ++p) {           // B tile 128x64 (rows = n)
      int r = p * 32 + sr;
      int row = n0 + r;
      int kg = k0 + so * 8;
      uint4 v = make_uint4(0, 0, 0, 0);
      if (row < g.N && kg + 8 <= g.Kreal)
        v = *(const uint4*)(Bb + (long)row * g.ldb + kg);
      *(uint4*)((char*)Bs + ((r * 128 + so * 16) ^ ((r & 7) << 4))) = v;
    }
    __syncthreads();
    #pragma unroll
    for (int ks = 0; ks < 2; ++ks) {
      bf16x8 af[4], bfr[4];
      #pragma unroll
      for (int i = 0; i < 4; ++i) {
        int ra = wr * 64 + i * 16 + (lane & 15);
        af[i] = *(const bf16x8*)((const char*)As +
                 ((ra * 128 + ks * 64 + (lane >> 4) * 16) ^ ((ra & 7) << 4)));
        int rb = wc * 64 + i * 16 + (lane & 15);
        bfr[i] = *(const bf16x8*)((const char*)Bs +
                 ((rb * 128 + ks * 64 + (lane >> 4) * 16) ^ ((rb & 7) << 4)));
      }
      #pragma unroll
      for (int i = 0; i < 4; ++i)
        #pragma unroll
        for (int j = 0; j < 4; ++j)
          acc[i][j] = __builtin_amdgcn_mfma_f32_16x16x32_bf16(af[i], bfr[j], acc[i][j], 0, 0, 0);
    }
  }
  // ---- epilogue: D col = lane&15 (n), row = (lane>>4)*4 + r (m) ----
  const long cz = (long)z * g.cStride;
  #pragma unroll
  for (int i = 0; i < 4; ++i) {
    int rbase = m0 + wr * 64 + i * 16 + ((lane >> 4) << 2);
    #pragma unroll
    for (int j = 0; j < 4; ++j) {
      int col = n0 + wc * 64 + j * 16 + (lane & 15);
      #pragma unroll
      for (int r = 0; r < 4; ++r) {
        int row = rbase + r;
        float v = acc[i][j][r];
        if (OUT == 0) {
          if (row < g.M && col < g.N)
            ((float*)g.C)[cz + (long)row * g.ldc + col] = v;
        } else if (OUT == 1) {
          if (row < g.M && col < g.N) {
            v += g.bias[(long)z * g.biasStride + col];
            ((__hip_bfloat16*)g.C)[cz + (long)row * g.ldc + col] = __float2bfloat16(v);
          }
        } else if (OUT == 3) {
          if (row < g.M)
            ((__hip_bfloat16*)g.C)[cz + (long)row * g.ldc + col] =
                __float2bfloat16(col < g.N ? v : 0.f);
        } else {  // OUT == 5: +bf16 res, relu, bf16 out
          if (row < g.M && col < g.N) {
            v += __bfloat162float(g.Res[(long)z * g.rStride + (long)row * g.ldc + col]);
            v = fmaxf(v, 0.f);
            ((__hip_bfloat16*)g.C)[cz + (long)row * g.ldc + col] = __float2bfloat16(v);
          }
        }
      }
    }
  }
}

// ---------------- fused prep: whh/gcnW/emb/wih -> bf16(+pad), biasC ----------
struct PrepArgs {
  const float* whh[4];    // tgt, tgc, sgt, sgc (each [2][768][256])
  const float* gcnW[2];   // task, shared (each [2][512][512])
  const float* emb;       // [30000][300]
  const float* wih[4];    // each [2][768][300]
  const float* bih[4];
  const float* bhh[4];
  __hip_bfloat16 *whhbf, *gcnWbf, *embbf;
  __hip_bfloat16* wihbf[4];
  float* biasC;           // [4][2][768]
};

constexpr long PR0 = 1572864;            // whh
constexpr long PR1 = PR0 + 1048576;      // gcnW
constexpr long PR2 = PR1 + 9120000;      // emb pad 304
constexpr long PR3 = PR2 + 1867776;      // wih pad 304 (4x 466944)
constexpr long PR4 = PR3 + 6144;         // biasC

__global__ __launch_bounds__(256) void prep_k(PrepArgs a) {
  long i = (long)blockIdx.x * 256 + threadIdx.x;
  if (i >= PR4) return;
  if (i < PR0) {
    int zz = (int)(i / 196608);
    long rem = i - (long)zz * 196608;
    a.whhbf[i] = __float2bfloat16(a.whh[zz >> 1][(long)(zz & 1) * 196608 + rem]);
  } else if (i < PR1) {
    long j = i - PR0;
    a.gcnWbf[j] = __float2bfloat16(a.gcnW[j / 524288][j % 524288]);
  } else if (i < PR2) {
    long j = i - PR1;
    long r = j / 304;
    int c = (int)(j - r * 304);
    a.embbf[j] = __float2bfloat16(c < 300 ? a.emb[r * 300 + c] : 0.f);
  } else if (i < PR3) {
    long j = i - PR2;
    int w = (int)(j / 466944);
    long k = j - (long)w * 466944;
    long r = k / 304;
    int c = (int)(k - r * 304);
    a.wihbf[w][k] = __float2bfloat16(c < 300 ? a.wih[w][r * 300 + c] : 0.f);
  } else {
    long j = i - PR3;
    int w = (int)(j / 1536);
    int k = (int)(j - (long)w * 1536);
    a.biasC[(long)w * 1536 + k] = a.bih[w][k] + ((k % 768) < 512 ? a.bhh[w][k] : 0.f);
  }
}

// ---------------- GRU recurrence: MFMA persistent-RNN, ALL 8 chains ----------
// grid (8,1,8): z = side*4 + sq*2 + dir; blockIdx.x = 16-batch group (64 blocks).
// R10 structure (measured floor): 512 thr = 2 waves/SIMD, Af 192 VGPR resident,
// h in f32 regs, bf16 h mirror in single swizzled LDS dbuf, gi register
// prefetch one step ahead, RHU pack, lgkmcnt-only barrier.
struct RecArgs {
  const __hip_bfloat16* whhbf;    // [8][768][256], z = side*4+sq*2+dir
  const __hip_bfloat16* gi[4];    // {task_t, task_c, shared_t, shared_c}
  const float* bhh[4];
  __hip_bfloat16* nodebf;         // [2][128][250][512]
};

__global__ __launch_bounds__(512, 2) void gru_rec_k(RecArgs a) {
  __shared__ __align__(16) char hbuf[2][8192];   // [buf][batch16][k256] bf16, swz
  const int z = blockIdx.z;
  const int side = z >> 2, sq = (z >> 1) & 1, dir = z & 1;
  const int gidx = side * 2 + sq;
  const int T = sq ? CL : TL;
  const int toff = sq ? TL : 0;
  const __hip_bfloat16* gi = a.gi[gidx] + (long)dir * B_ * T * 768;
  const float* bhh = a.bhh[gidx] + dir * 768;
  const __hip_bfloat16* whh = a.whhbf + (long)z * 768 * 256;
  __hip_bfloat16* nodeb = a.nodebf + (long)side * NODE_ELE;
  const int b0 = blockIdx.x * 16;
  const int tid = threadIdx.x;
  const int lane = tid & 63, wv = tid >> 6;
  const int bcol = lane & 15, g4 = lane >> 4;
  const int u0 = wv * 32 + g4 * 4;
  const int swzh = (bcol & 15) << 4;   // bijective within 512B h-row

  bf16x8 Af[3][2][8];
  #pragma unroll
  for (int g = 0; g < 3; ++g)
    #pragma unroll
    for (int h = 0; h < 2; ++h)
      #pragma unroll
      for (int kt = 0; kt < 8; ++kt) {
        int row = g * 256 + wv * 32 + h * 16 + bcol;
        int col = kt * 32 + g4 * 8;
        Af[g][h][kt] = *(const bf16x8*)(whh + (long)row * 256 + col);
      }
  *(uint4*)&hbuf[0][tid * 16] = make_uint4(0, 0, 0, 0);
  const float4 bn0 = *(const float4*)&bhh[512 + u0];
  const float4 bn1 = *(const float4*)&bhh[512 + u0 + 16];
  __syncthreads();

  const __hip_bfloat16* gip = gi + ((long)(b0 + bcol) * T + (dir ? T - 1 : 0)) * 768 + u0;
  __hip_bfloat16* np = nodeb + ((long)(b0 + bcol) * NNODE + toff + (dir ? T - 1 : 0)) * D_
                       + dir * H_ + u0;
  const long gistep = dir ? -768L : 768L;
  const long nstep  = dir ? -(long)D_ : (long)D_;
  int cur = 0;

  float hreg[2][4];
  #pragma unroll
  for (int h = 0; h < 2; ++h)
    #pragma unroll
    for (int r = 0; r < 4; ++r) hreg[h][r] = 0.f;

  // gi preload for t=0
  uint2 gv[3][2];
  #pragma unroll
  for (int g = 0; g < 3; ++g)
    #pragma unroll
    for (int h = 0; h < 2; ++h)
      gv[g][h] = *(const uint2*)(gip + g * 256 + h * 16);

  for (int t = 0; t < T; ++t) {
    // ---- MFMA: gates for (32 units) x (16 batch), bf16 h ----
    const char* hib = &hbuf[cur][0];
    f32x4 c[3][2];
    #pragma unroll
    for (int g = 0; g < 3; ++g)
      #pragma unroll
      for (int h = 0; h < 2; ++h) c[g][h] = (f32x4){0.f, 0.f, 0.f, 0.f};
    const int rb = bcol * 512 + g4 * 16;
    #pragma unroll
    for (int kt = 0; kt < 8; ++kt) {
      bf16x8 bh = *(const bf16x8*)(hib + ((rb + kt * 64) ^ swzh));
      #pragma unroll
      for (int g = 0; g < 3; ++g)
        #pragma unroll
        for (int h = 0; h < 2; ++h)
          c[g][h] = __builtin_amdgcn_mfma_f32_16x16x32_bf16(Af[g][h][kt], bh, c[g][h], 0, 0, 0);
    }

    // ---- activation (h_old exact in regs; r,z bias pre-folded into gi) ----
    #pragma unroll
    for (int h = 0; h < 2; ++h) {
      float4 bn = h ? bn1 : bn0;
      #pragma unroll
      for (int r = 0; r < 4; ++r) {
        float bnv = (r == 0) ? bn.x : (r == 1) ? bn.y : (r == 2) ? bn.z : bn.w;
        float rr = sigf(bfsel(gv[0][h], r) + c[0][h][r]);
        float zz = sigf(bfsel(gv[1][h], r) + c[1][h][r]);
        float nn = tanhf_(bfsel(gv[2][h], r) + rr * (c[2][h][r] + bnv));
        hreg[h][r] = (1.f - zz) * nn + zz * hreg[h][r];
      }
    }

    // ---- issue gi loads for t+1 (in flight across pack+barrier+next MFMA) ----
    {
      const __hip_bfloat16* gn = (t + 1 < T) ? gip + gistep : gip;
      gip = gn;
      #pragma unroll
      for (int g = 0; g < 3; ++g)
        #pragma unroll
        for (int h = 0; h < 2; ++h)
          gv[g][h] = *(const uint2*)(gn + g * 256 + h * 16);
    }

    // ---- pack h -> bf16 (round-half-up); store to node + next h-buffer ----
    const int ob0 = bcol * 512 + u0 * 2;
    char* hibn = &hbuf[cur ^ 1][0];
    #pragma unroll
    for (int h = 0; h < 2; ++h) {
      unsigned hb[4];
      #pragma unroll
      for (int r = 0; r < 4; ++r)
        hb[r] = (f2bits(hreg[h][r]) + 0x8000u) & 0xFFFF0000u;
      uint2 hiw;
      hiw.x = (hb[0] >> 16) | hb[1];
      hiw.y = (hb[2] >> 16) | hb[3];
      *(uint2*)(np + h * 16) = hiw;                       // node (fire-and-forget)
      *(uint2*)(hibn + ((ob0 + h * 32) ^ swzh)) = hiw;    // next-step h
    }
    np += nstep;
    asm volatile("s_waitcnt lgkmcnt(0)" ::: "memory");
    __builtin_amdgcn_sched_barrier(0);
    __builtin_amdgcn_s_barrier();
    cur ^= 1;
  }
}

// ---------------- attention over claims (bf16 node, both sides) ----------------
__global__ __launch_bounds__(256) void attn_k(const __hip_bfloat16* nodeAll,
                                              float* wT, float* wS) {
  int b = blockIdx.x, side = blockIdx.y;
  const __hip_bfloat16* node = nodeAll + (long)side * NODE_ELE;
  float* w = side ? wS : wT;
  __shared__ float tl[512];
  __shared__ float sc[CL];
  int tid = threadIdx.x;
  {
    const __hip_bfloat16* tr = node + ((long)b * NNODE + (TL - 1)) * D_;
    tl[tid]       = __bfloat162float(tr[tid]);
    tl[tid + 256] = __bfloat162float(tr[tid + 256]);
  }
  __syncthreads();
  int wid = tid >> 6, lane = tid & 63;
  for (int c = wid; c < CL; c += 4) {
    const __hip_bfloat16* row = node + ((long)b * NNODE + TL + c) * D_;
    uint4 v = *(const uint4*)(row + lane * 8);
    const float* tp = &tl[lane * 8];
    float acc = bits2f(v.x << 16)         * tp[0] + bits2f(v.x & 0xFFFF0000u) * tp[1]
              + bits2f(v.y << 16)         * tp[2] + bits2f(v.y & 0xFFFF0000u) * tp[3]
              + bits2f(v.z << 16)         * tp[4] + bits2f(v.z & 0xFFFF0000u) * tp[5]
              + bits2f(v.w << 16)         * tp[6] + bits2f(v.w & 0xFFFF0000u) * tp[7];
    #pragma unroll
    for (int o = 32; o; o >>= 1) acc += __shfl_xor(acc, o, 64);
    if (lane == 0) sc[c] = acc;
  }
  __syncthreads();
  if (wid == 0) {
    float v[4]; float m = -1e30f;
    #pragma unroll
    for (int i = 0; i < 4; ++i) {
      int c = lane + 64 * i;
      v[i] = (c < CL) ? sc[c] : -1e30f;
      m = fmaxf(m, v[i]);
    }
    #pragma unroll
    for (int o = 32; o; o >>= 1) m = fmaxf(m, __shfl_xor(m, o, 64));
    float s = 0.f;
    #pragma unroll
    for (int i = 0; i < 4; ++i) {
      int c = lane + 64 * i;
      v[i] = (c < CL) ? expf(v[i] - m) : 0.f;
      s += v[i];
    }
    #pragma unroll
    for (int o = 32; o; o >>= 1) s += __shfl_xor(s, o, 64);
    float inv = 1.f / s;
    #pragma unroll
    for (int i = 0; i < 4; ++i) {
      int c = lane + 64 * i;
      if (c < CL) w[(long)b * CL + c] = v[i] * inv;
    }
  }
}

// ---------------- row softmax: f32 in (ld 256, len 250) -> bf16 out, 0-pad ----
__global__ __launch_bounds__(256) void softmaxbf_k(const float* in, __hip_bfloat16* out) {
  int row = blockIdx.x * 4 + (threadIdx.x >> 6);
  int lane = threadIdx.x & 63;
  const float* p = in + (long)row * 256;
  __hip_bfloat16* q = out + (long)row * 256;
  float v[4]; float m = -1e30f;
  #pragma unroll
  for (int i = 0; i < 4; ++i) {
    int c = lane + i * 64;
    v[i] = (c < 250) ? p[c] : -1e30f;
    m = fmaxf(m, v[i]);
  }
  #pragma unroll
  for (int o = 32; o; o >>= 1) m = fmaxf(m, __shfl_xor(m, o, 64));
  float s = 0.f;
  #pragma unroll
  for (int i = 0; i < 4; ++i) {
    int c = lane + i * 64;
    if (c < 250) { v[i] = __expf(v[i] - m); s += v[i]; }
  }
  #pragma unroll
  for (int o = 32; o; o >>= 1) s += __shfl_xor(s, o, 64);
  float inv = 1.f / s;
  #pragma unroll
  for (int i = 0; i < 4; ++i) {
    int c = lane + i * 64;
    q[c] = __float2bfloat16((c < 250) ? v[i] * inv : 0.f);
  }
}

// ---------------- weighted claim pooling (bf16 node, both sides) ----------------
__global__ __launch_bounds__(256) void rep_k(const __hip_bfloat16* nodeAll,
                                             const float* wT, const float* wS,
                                             float* rep) {
  int b = blockIdx.x, side = blockIdx.y;
  const __hip_bfloat16* node = nodeAll + (long)side * NODE_ELE;
  const float* w = side ? wS : wT;
  __shared__ float wl[CL];
  int tid = threadIdx.x;
  if (tid < CL) wl[tid] = w[(long)b * CL + tid];
  __syncthreads();
  #pragma unroll
  for (int h = 0; h < 2; ++h) {
    int d = tid + h * 256;
    float acc = 0.f;
    for (int c = 0; c < CL; ++c)
      acc = fmaf(wl[c], __bfloat162float(node[((long)b * NNODE + TL + c) * D_ + d]), acc);
    rep[((long)side * B_ + b) * D_ + d] = acc;
  }
}

// ---------------- final linear ----------------
__global__ __launch_bounds__(256) void final_k(const float* rep, const float* linW,
                                               const float* linb, float* out) {
  int b = blockIdx.x, tid = threadIdx.x;
  float a0 = 0.f, a1 = 0.f, a2 = 0.f;
  for (int d = tid; d < 1024; d += 256) {
    float x = rep[(long)(d >> 9) * (B_ * D_) + (long)b * D_ + (d & 511)];
    a0 = fmaf(x, linW[d], a0);
    a1 = fmaf(x, linW[1024 + d], a1);
    a2 = fmaf(x, linW[2048 + d], a2);
  }
  #pragma unroll
  for (int o = 32; o; o >>= 1) {
    a0 += __shfl_xor(a0, o, 64);
    a1 += __shfl_xor(a1, o, 64);
    a2 += __shfl_xor(a2, o, 64);
  }
  __shared__ float red[3][4];
  int wid = tid >> 6, lane = tid & 63;
  if (lane == 0) { red[0][wid] = a0; red[1][wid] = a1; red[2][wid] = a2; }
  __syncthreads();
  if (tid == 0) {
    out[b * 3 + 0] = red[0][0] + red[0][1] + red[0][2] + red[0][3] + linb[0];
    out[b * 3 + 1] = red[1][0] + red[1][1] + red[1][2] + red[1][3] + linb[1];
    out[b * 3 + 2] = red[2][0] + red[2][1] + red[2][2] + red[2][3] + linb[2];
  }
}

// ---------------- diagnostic ----------------
__global__ void diag_k(float* out, int n, float v) {
  int i = blockIdx.x * blockDim.x + threadIdx.x;
  if (i < n) out[i] = v;
}

} // namespace

extern "C" void kernel_launch(void* const* d_in, const int* in_sizes, int n_in,
                              void* d_out, int out_size, void* d_ws, size_t ws_size,
                              hipStream_t stream) {
  const int* task_target   = (const int*)d_in[1];
  const int* shared_target = (const int*)d_in[2];
  const int* task_claim    = (const int*)d_in[3];
  const int* shared_claim  = (const int*)d_in[4];
  const float* emb      = (const float*)d_in[9];
  const float* tgt_wih  = (const float*)d_in[10];
  const float* tgt_whh  = (const float*)d_in[11];
  const float* tgt_bih  = (const float*)d_in[12];
  const float* tgt_bhh  = (const float*)d_in[13];
  const float* tgc_wih  = (const float*)d_in[14];
  const float* tgc_whh  = (const float*)d_in[15];
  const float* tgc_bih  = (const float*)d_in[16];
  const float* tgc_bhh  = (const float*)d_in[17];
  const float* sgt_wih  = (const float*)d_in[18];
  const float* sgt_whh  = (const float*)d_in[19];
  const float* sgt_bih  = (const float*)d_in[20];
  const float* sgt_bhh  = (const float*)d_in[21];
  const float* sgc_wih  = (const float*)d_in[22];
  const float* sgc_whh  = (const float*)d_in[23];
  const float* sgc_bih  = (const float*)d_in[24];
  const float* sgc_bhh  = (const float*)d_in[25];
  const float* gcnW_task   = (const float*)d_in[26];
  const float* gcnW_shared = (const float*)d_in[27];
  const float* linW = (const float*)d_in[28];
  const float* linb = (const float*)d_in[29];
  float* out = (float*)d_out;

  // ---- workspace plan (bytes); total ~268.1 MB <= 256 MiB ----
  const size_t SZ_WHH   = 3145728;
  const size_t SZ_GCNW  = 2097152;
  const size_t SZ_BIASC = 24576;
  const size_t SZ_ARENA = 196608000;    // gi all 4 (phase A) / GCN scratch (phase B)
  const size_t SZ_NODE  = 65536000;     // 2 sides x 128x250x512 bf16
  const size_t SZ_W     = 102400;
  const size_t SZ_REP   = 524288;
  const size_t NEED = SZ_WHH + SZ_GCNW + SZ_BIASC + SZ_ARENA + SZ_NODE
                      + 2 * SZ_W + SZ_REP + 4096;

  if (ws_size < NEED) {
    diag_k<<<(out_size + 255) / 256, 256, 0, stream>>>(out, out_size,
                                                       (float)(ws_size >> 20));
    return;
  }

  char* p = (char*)d_ws;
  auto alloc = [&](size_t bytes) { char* r = p; p += (bytes + 255) & ~(size_t)255; return r; };
  __hip_bfloat16* whhbf  = (__hip_bfloat16*)alloc(SZ_WHH);
  __hip_bfloat16* gcnWbf = (__hip_bfloat16*)alloc(SZ_GCNW);   // [side][layer][512][512]
  float* biasC = (float*)alloc(SZ_BIASC);                     // [4][2][768]
  char* arena  = alloc(SZ_ARENA);
  char* nodeC  = alloc(SZ_NODE);
  float* wT    = (float*)alloc(SZ_W);
  float* wS    = (float*)alloc(SZ_W);
  float* rep   = (float*)alloc(SZ_REP);
  __hip_bfloat16* nodebf = (__hip_bfloat16*)nodeC;

  // phase-A views: gi for all 4 GRUs in arena; emb/wih conversions alias nodebf
  __hip_bfloat16* gi_tt = (__hip_bfloat16*)(arena);
  __hip_bfloat16* gi_tc = (__hip_bfloat16*)(arena + 19660800);
  __hip_bfloat16* gi_st = (__hip_bfloat16*)(arena + 98304000);
  __hip_bfloat16* gi_sc = (__hip_bfloat16*)(arena + 117964800);
  __hip_bfloat16* embbf = (__hip_bfloat16*)(nodeC);                  // [30000][304]
  __hip_bfloat16* wihbf[4] = {                                       // [2][768][304] each
    (__hip_bfloat16*)(nodeC + 18240000),
    (__hip_bfloat16*)(nodeC + 19173888),
    (__hip_bfloat16*)(nodeC + 20107776),
    (__hip_bfloat16*)(nodeC + 21041664)};
  // phase-B (GCN) views of arena, both sides fused (z = 0..255)
  __hip_bfloat16* tmpbf  = (__hip_bfloat16*)(arena);                 // [256][250][512]
  __hip_bfloat16* corrbf = (__hip_bfloat16*)(arena + 65536000);      // [256][250][256]
  float*          corrF  = (float*)(arena + 98304000);               // [256][250][256] f32
  __hip_bfloat16* transT = (__hip_bfloat16*)(arena + 98304000);      // aliases corrF (dead)

  // ---- fused prep (1 dispatch) ----
  {
    PrepArgs pa;
    pa.whh[0] = tgt_whh; pa.whh[1] = tgc_whh; pa.whh[2] = sgt_whh; pa.whh[3] = sgc_whh;
    pa.gcnW[0] = gcnW_task; pa.gcnW[1] = gcnW_shared;
    pa.emb = emb;
    pa.wih[0] = tgt_wih; pa.wih[1] = tgc_wih; pa.wih[2] = sgt_wih; pa.wih[3] = sgc_wih;
    pa.bih[0] = tgt_bih; pa.bih[1] = tgc_bih; pa.bih[2] = sgt_bih; pa.bih[3] = sgc_bih;
    pa.bhh[0] = tgt_bhh; pa.bhh[1] = tgc_bhh; pa.bhh[2] = sgt_bhh; pa.bhh[3] = sgc_bhh;
    pa.whhbf = whhbf; pa.gcnWbf = gcnWbf; pa.embbf = embbf;
    pa.wihbf[0] = wihbf[0]; pa.wihbf[1] = wihbf[1];
    pa.wihbf[2] = wihbf[2]; pa.wihbf[3] = wihbf[3];
    pa.biasC = biasC;
    prep_k<<<(int)((PR4 + 255) / 256), 256, 0, stream>>>(pa);
  }

  // ---- projections: gi = emb[tok] @ Wih^T + biasC (bf16) ----
  auto proj = [&](const int* idx, __hip_bfloat16* wih, const float* bias,
                  __hip_bfloat16* gi, int Mrows, int gx) {
    BGemmArgs ga{};
    ga.A = embbf; ga.idx = idx; ga.B = wih; ga.bias = bias; ga.C = gi;
    ga.aStride = 0; ga.bStride = 768L * 304; ga.biasStride = 768;
    ga.cStride = (long)Mrows * 768; ga.zShiftA = 0;
    ga.M = Mrows; ga.N = 768; ga.Kreal = 304; ga.lda = 304; ga.ldb = 304; ga.ldc = 768;
    bgemm_k<true, 1><<<dim3(gx, 6, 2), 256, 0, stream>>>(ga);
  };
  proj(task_target,   wihbf[0], biasC,        gi_tt, 6400, 50);
  proj(task_claim,    wihbf[1], biasC + 1536, gi_tc, 25600, 200);
  proj(shared_target, wihbf[2], biasC + 3072, gi_st, 6400, 50);
  proj(shared_claim,  wihbf[3], biasC + 4608, gi_sc, 25600, 200);

  // ---- all 8 GRU chains in ONE dispatch (writes nodebf over emb/wih alias) ----
  RecArgs ra;
  ra.whhbf = whhbf;
  ra.gi[0] = gi_tt; ra.gi[1] = gi_tc; ra.gi[2] = gi_st; ra.gi[3] = gi_sc;
  ra.bhh[0] = tgt_bhh; ra.bhh[1] = tgc_bhh; ra.bhh[2] = sgt_bhh; ra.bhh[3] = sgc_bhh;
  ra.nodebf = nodebf;
  gru_rec_k<<<dim3(8, 1, 8), 512, 0, stream>>>(ra);

  // ---- stance attention, both sides ----
  attn_k<<<dim3(128, 2), 256, 0, stream>>>(nodebf, wT, wS);

  // ---- GCN 2 layers, BOTH sides fused (z = 0..255; side = z>>7) ----
  for (int layer = 0; layer < 2; ++layer) {
    const __hip_bfloat16* inbf = layer ? tmpbf : nodebf;   // z-contiguous across sides
    BGemmArgs ca{};   // corr = in @ in^T (f32)
    ca.A = inbf; ca.B = inbf; ca.C = corrF;
    ca.aStride = 128000; ca.bStride = 128000; ca.cStride = 64000; ca.zShiftA = 0;
    ca.M = 250; ca.N = 250; ca.Kreal = 512; ca.lda = 512; ca.ldb = 512; ca.ldc = 256;
    bgemm_k<false, 0><<<dim3(2, 2, 256), 256, 0, stream>>>(ca);
    softmaxbf_k<<<16000, 256, 0, stream>>>(corrF, corrbf);
    BGemmArgs ta{};   // trans^T = W[side] @ in^T (bf16, 0-pad cols 250..255)
    ta.A = gcnWbf + (long)layer * 262144; ta.B = inbf; ta.C = transT;
    ta.aStride = 524288; ta.bStride = 128000; ta.cStride = 131072; ta.zShiftA = 7;
    ta.M = 512; ta.N = 250; ta.Kreal = 512; ta.lda = 512; ta.ldb = 512; ta.ldc = 256;
    bgemm_k<false, 3><<<dim3(4, 2, 256), 256, 0, stream>>>(ta);
    BGemmArgs aa{};   // out = relu(res + corr @ trans), all bf16
    aa.A = corrbf; aa.B = transT; aa.Res = inbf;
    aa.C = layer ? (void*)nodebf : (void*)tmpbf;
    aa.aStride = 64000; aa.bStride = 131072; aa.cStride = 128000;
    aa.rStride = 128000; aa.zShiftA = 0;
    aa.M = 250; aa.N = 512; aa.Kreal = 256; aa.lda = 256; aa.ldb = 256; aa.ldc = 512;
    bgemm_k<false, 5><<<dim3(2, 4, 256), 256, 0, stream>>>(aa);
  }

  // ---- pooling (post-GCN node in nodebf), final linear ----
  rep_k<<<dim3(128, 2), 256, 0, stream>>>(nodebf, wT, wS, rep);
  final_k<<<dim3(128), 256, 0, stream>>>(rep, linW, linb, out);
}

// Round 14
// 1527.486 us; speedup vs baseline: 1.2367x; 1.0866x over previous
//
#include <hip/hip_runtime.h>
#include <hip/hip_bf16.h>

namespace {

constexpr int B_  = 128;
constexpr int TL  = 50, CL = 200, NNODE = 250;
constexpr int H_  = 256, D_ = 512;
constexpr long NODE_ELE = 128L * 250 * 512;   // per side

typedef __attribute__((ext_vector_type(8))) short bf16x8;
typedef __attribute__((ext_vector_type(4))) float f32x4;

__device__ inline float bits2f(unsigned v) { union { unsigned u; float f; } c; c.u = v; return c.f; }
__device__ inline unsigned f2bits(float x) { union { float f; unsigned u; } c; c.f = x; return c.u; }
__device__ inline unsigned short bfbits(float x) {
  __hip_bfloat16 b = __float2bfloat16(x);
  return *(unsigned short*)&b;
}
__device__ inline float bfsel(uint2 v, int r) {        // r-th bf16 of a 4-pack
  unsigned w = (r < 2) ? v.x : v.y;
  return bits2f((r & 1) ? (w & 0xFFFF0000u) : (w << 16));
}
__device__ inline float sigf(float x)  { return 1.f / (1.f + __expf(-x)); }
__device__ inline float tanhf_(float x){ return 1.f - 2.f / (__expf(2.f * x) + 1.f); }

// =============== bf16 MFMA GEMM: C[z] = A[za] @ B[z]^T (B is [N][K]) ==========
// Staging: global_load_lds 16B direct-to-LDS, double-buffered, prefetch tile
// kt+1 before computing kt (m97 structure). LDS dest LINEAR; source column
// pre-swizzled (rule 21); ds_read applies matching XOR. Requires K % 64 == 0.
// OOB rows stage garbage (no zero-fill): safe because garbage rows are never
// stored, garbage cols are masked (softmax) or overwritten (OUT=3), and all
// overreads stay inside the workspace arena.
// za = z >> zShiftA (per-side weights at zShiftA=7). OUT modes:
// 0: f32 out. 1: +bias -> bf16. 3: bf16 out, zero-fill cols [N,256).
// 5: +bf16 Res, relu -> bf16 out.
struct BGemmArgs {
  const __hip_bfloat16* A; const __hip_bfloat16* B;
  const int* idx; const float* bias; const __hip_bfloat16* Res;
  void* C;
  long aStride, bStride, biasStride, cStride, rStride;
  int M, N, Kreal, lda, ldb, ldc, zShiftA;
};

template<bool GATHER, int OUT>
__global__ __launch_bounds__(256) void bgemm_k(BGemmArgs g) {
  __shared__ __align__(16) char As[2][16384];   // [buf][128 rows][64 k] bf16 linear
  __shared__ __align__(16) char Bs[2][16384];
  const int z = blockIdx.z;
  const int m0 = blockIdx.x * 128, n0 = blockIdx.y * 128;
  const int tid = threadIdx.x;
  const int lane = tid & 63, wv = tid >> 6;
  const int wr = wv >> 1, wc = wv & 1;                    // wave -> 64x64 quadrant
  const __hip_bfloat16* Ab = GATHER ? g.A : g.A + (long)(z >> g.zShiftA) * g.aStride;
  const __hip_bfloat16* Bb = g.B + (long)z * g.bStride;

  // staging geometry: octet o = c*256 + tid; row = o>>3, ko = o&7;
  // source col-octet = ko ^ (row&7)  (inverse swizzle; LDS dest stays linear)
  long asrc[4], bsrc[4];
  int ldso[4];
  #pragma unroll
  for (int c2 = 0; c2 < 4; ++c2) {
    int o = c2 * 256 + tid;
    int row = o >> 3, ko = o & 7;
    int colel = 8 * (ko ^ (row & 7));
    long arow = GATHER ? (long)g.idx[m0 + row] * g.lda : (long)(m0 + row) * g.lda;
    asrc[c2] = arow + colel;
    bsrc[c2] = (long)(n0 + row) * g.ldb + colel;
    ldso[c2] = o * 16;
  }

  f32x4 acc[4][4];
  #pragma unroll
  for (int i = 0; i < 4; ++i)
    #pragma unroll
    for (int j = 0; j < 4; ++j) acc[i][j] = (f32x4){0.f, 0.f, 0.f, 0.f};

  const int KT = g.Kreal >> 6;
  // prologue: stage tile 0 into buf 0
  #pragma unroll
  for (int c2 = 0; c2 < 4; ++c2) {
    __builtin_amdgcn_global_load_lds(
        (const __attribute__((address_space(1))) unsigned*)(Ab + asrc[c2]),
        (__attribute__((address_space(3))) unsigned*)(&As[0][0] + ldso[c2]), 16, 0, 0);
    __builtin_amdgcn_global_load_lds(
        (const __attribute__((address_space(1))) unsigned*)(Bb + bsrc[c2]),
        (__attribute__((address_space(3))) unsigned*)(&Bs[0][0] + ldso[c2]), 16, 0, 0);
  }
  __syncthreads();

  int buf = 0;
  for (int kt = 0; kt < KT; ++kt) {
    if (kt + 1 < KT) {                       // prefetch next tile into buf^1
      long ko = (long)(kt + 1) * 64;
      #pragma unroll
      for (int c2 = 0; c2 < 4; ++c2) {
        __builtin_amdgcn_global_load_lds(
            (const __attribute__((address_space(1))) unsigned*)(Ab + asrc[c2] + ko),
            (__attribute__((address_space(3))) unsigned*)(&As[buf ^ 1][0] + ldso[c2]), 16, 0, 0);
        __builtin_amdgcn_global_load_lds(
            (const __attribute__((address_space(1))) unsigned*)(Bb + bsrc[c2] + ko),
            (__attribute__((address_space(3))) unsigned*)(&Bs[buf ^ 1][0] + ldso[c2]), 16, 0, 0);
      }
    }
    const char* ab = &As[buf][0];
    const char* bb = &Bs[buf][0];
    #pragma unroll
    for (int ks = 0; ks < 2; ++ks) {
      bf16x8 af[4], bfr[4];
      #pragma unroll
      for (int i = 0; i < 4; ++i) {
        int ra = wr * 64 + i * 16 + (lane & 15);
        af[i] = *(const bf16x8*)(ab + ((ra * 128 + ks * 64 + (lane >> 4) * 16) ^ ((ra & 7) << 4)));
        int rb = wc * 64 + i * 16 + (lane & 15);
        bfr[i] = *(const bf16x8*)(bb + ((rb * 128 + ks * 64 + (lane >> 4) * 16) ^ ((rb & 7) << 4)));
      }
      #pragma unroll
      for (int i = 0; i < 4; ++i)
        #pragma unroll
        for (int j = 0; j < 4; ++j)
          acc[i][j] = __builtin_amdgcn_mfma_f32_16x16x32_bf16(af[i], bfr[j], acc[i][j], 0, 0, 0);
    }
    __syncthreads();                          // drains prefetch vmcnt + read done
    buf ^= 1;
  }

  // ---- epilogue: D col = lane&15 (n), row = (lane>>4)*4 + r (m) ----
  const long cz = (long)z * g.cStride;
  #pragma unroll
  for (int i = 0; i < 4; ++i) {
    int rbase = m0 + wr * 64 + i * 16 + ((lane >> 4) << 2);
    #pragma unroll
    for (int j = 0; j < 4; ++j) {
      int col = n0 + wc * 64 + j * 16 + (lane & 15);
      #pragma unroll
      for (int r = 0; r < 4; ++r) {
        int row = rbase + r;
        float v = acc[i][j][r];
        if (OUT == 0) {
          if (row < g.M && col < g.N)
            ((float*)g.C)[cz + (long)row * g.ldc + col] = v;
        } else if (OUT == 1) {
          if (row < g.M && col < g.N) {
            v += g.bias[(long)z * g.biasStride + col];
            ((__hip_bfloat16*)g.C)[cz + (long)row * g.ldc + col] = __float2bfloat16(v);
          }
        } else if (OUT == 3) {
          if (row < g.M)
            ((__hip_bfloat16*)g.C)[cz + (long)row * g.ldc + col] =
                __float2bfloat16(col < g.N ? v : 0.f);
        } else {  // OUT == 5: +bf16 res, relu, bf16 out
          if (row < g.M && col < g.N) {
            v += __bfloat162float(g.Res[(long)z * g.rStride + (long)row * g.ldc + col]);
            v = fmaxf(v, 0.f);
            ((__hip_bfloat16*)g.C)[cz + (long)row * g.ldc + col] = __float2bfloat16(v);
          }
        }
      }
    }
  }
}

// ---------------- fused prep: whh/gcnW/emb/wih -> bf16(+pad 320), biasC -------
struct PrepArgs {
  const float* whh[4];    // tgt, tgc, sgt, sgc (each [2][768][256])
  const float* gcnW[2];   // task, shared (each [2][512][512])
  const float* emb;       // [30000][300]
  const float* wih[4];    // each [2][768][300]
  const float* bih[4];
  const float* bhh[4];
  __hip_bfloat16 *whhbf, *gcnWbf, *embbf;
  __hip_bfloat16* wihbf[4];
  float* biasC;           // [4][2][768]
};

constexpr long PR0 = 1572864;            // whh
constexpr long PR1 = PR0 + 1048576;      // gcnW
constexpr long PR2 = PR1 + 9600000;      // emb pad 320
constexpr long PR3 = PR2 + 1966080;      // wih pad 320 (4x 491520)
constexpr long PR4 = PR3 + 6144;         // biasC

__global__ __launch_bounds__(256) void prep_k(PrepArgs a) {
  long i = (long)blockIdx.x * 256 + threadIdx.x;
  if (i >= PR4) return;
  if (i < PR0) {
    int zz = (int)(i / 196608);
    long rem = i - (long)zz * 196608;
    a.whhbf[i] = __float2bfloat16(a.whh[zz >> 1][(long)(zz & 1) * 196608 + rem]);
  } else if (i < PR1) {
    long j = i - PR0;
    a.gcnWbf[j] = __float2bfloat16(a.gcnW[j / 524288][j % 524288]);
  } else if (i < PR2) {
    long j = i - PR1;
    long r = j / 320;
    int c = (int)(j - r * 320);
    a.embbf[j] = __float2bfloat16(c < 300 ? a.emb[r * 300 + c] : 0.f);
  } else if (i < PR3) {
    long j = i - PR2;
    int w = (int)(j / 491520);
    long k = j - (long)w * 491520;
    long r = k / 320;
    int c = (int)(k - r * 320);
    a.wihbf[w][k] = __float2bfloat16(c < 300 ? a.wih[w][r * 300 + c] : 0.f);
  } else {
    long j = i - PR3;
    int w = (int)(j / 1536);
    int k = (int)(j - (long)w * 1536);
    a.biasC[(long)w * 1536 + k] = a.bih[w][k] + ((k % 768) < 512 ? a.bhh[w][k] : 0.f);
  }
}

// ---------------- GRU recurrence: MFMA persistent-RNN, ALL 8 chains ----------
// R13 structure (measured floor ~802us): 512 thr = 2 waves/SIMD, Af 192 regs,
// h in f32 regs, bf16 h mirror in swizzled LDS dbuf, gi register prefetch,
// RHU pack, lgkmcnt-only barrier. UNCHANGED.
struct RecArgs {
  const __hip_bfloat16* whhbf;    // [8][768][256], z = side*4+sq*2+dir
  const __hip_bfloat16* gi[4];    // {task_t, task_c, shared_t, shared_c}
  const float* bhh[4];
  __hip_bfloat16* nodebf;         // [2][128][250][512]
};

__global__ __launch_bounds__(512, 2) void gru_rec_k(RecArgs a) {
  __shared__ __align__(16) char hbuf[2][8192];   // [buf][batch16][k256] bf16, swz
  const int z = blockIdx.z;
  const int side = z >> 2, sq = (z >> 1) & 1, dir = z & 1;
  const int gidx = side * 2 + sq;
  const int T = sq ? CL : TL;
  const int toff = sq ? TL : 0;
  const __hip_bfloat16* gi = a.gi[gidx] + (long)dir * B_ * T * 768;
  const float* bhh = a.bhh[gidx] + dir * 768;
  const __hip_bfloat16* whh = a.whhbf + (long)z * 768 * 256;
  __hip_bfloat16* nodeb = a.nodebf + (long)side * NODE_ELE;
  const int b0 = blockIdx.x * 16;
  const int tid = threadIdx.x;
  const int lane = tid & 63, wv = tid >> 6;
  const int bcol = lane & 15, g4 = lane >> 4;
  const int u0 = wv * 32 + g4 * 4;
  const int swzh = (bcol & 15) << 4;   // bijective within 512B h-row

  bf16x8 Af[3][2][8];
  #pragma unroll
  for (int g = 0; g < 3; ++g)
    #pragma unroll
    for (int h = 0; h < 2; ++h)
      #pragma unroll
      for (int kt = 0; kt < 8; ++kt) {
        int row = g * 256 + wv * 32 + h * 16 + bcol;
        int col = kt * 32 + g4 * 8;
        Af[g][h][kt] = *(const bf16x8*)(whh + (long)row * 256 + col);
      }
  *(uint4*)&hbuf[0][tid * 16] = make_uint4(0, 0, 0, 0);
  const float4 bn0 = *(const float4*)&bhh[512 + u0];
  const float4 bn1 = *(const float4*)&bhh[512 + u0 + 16];
  __syncthreads();

  const __hip_bfloat16* gip = gi + ((long)(b0 + bcol) * T + (dir ? T - 1 : 0)) * 768 + u0;
  __hip_bfloat16* np = nodeb + ((long)(b0 + bcol) * NNODE + toff + (dir ? T - 1 : 0)) * D_
                       + dir * H_ + u0;
  const long gistep = dir ? -768L : 768L;
  const long nstep  = dir ? -(long)D_ : (long)D_;
  int cur = 0;

  float hreg[2][4];
  #pragma unroll
  for (int h = 0; h < 2; ++h)
    #pragma unroll
    for (int r = 0; r < 4; ++r) hreg[h][r] = 0.f;

  // gi preload for t=0
  uint2 gv[3][2];
  #pragma unroll
  for (int g = 0; g < 3; ++g)
    #pragma unroll
    for (int h = 0; h < 2; ++h)
      gv[g][h] = *(const uint2*)(gip + g * 256 + h * 16);

  for (int t = 0; t < T; ++t) {
    // ---- MFMA: gates for (32 units) x (16 batch), bf16 h ----
    const char* hib = &hbuf[cur][0];
    f32x4 c[3][2];
    #pragma unroll
    for (int g = 0; g < 3; ++g)
      #pragma unroll
      for (int h = 0; h < 2; ++h) c[g][h] = (f32x4){0.f, 0.f, 0.f, 0.f};
    const int rb = bcol * 512 + g4 * 16;
    #pragma unroll
    for (int kt = 0; kt < 8; ++kt) {
      bf16x8 bh = *(const bf16x8*)(hib + ((rb + kt * 64) ^ swzh));
      #pragma unroll
      for (int g = 0; g < 3; ++g)
        #pragma unroll
        for (int h = 0; h < 2; ++h)
          c[g][h] = __builtin_amdgcn_mfma_f32_16x16x32_bf16(Af[g][h][kt], bh, c[g][h], 0, 0, 0);
    }

    // ---- activation (h_old exact in regs; r,z bias pre-folded into gi) ----
    #pragma unroll
    for (int h = 0; h < 2; ++h) {
      float4 bn = h ? bn1 : bn0;
      #pragma unroll
      for (int r = 0; r < 4; ++r) {
        float bnv = (r == 0) ? bn.x : (r == 1) ? bn.y : (r == 2) ? bn.z : bn.w;
        float rr = sigf(bfsel(gv[0][h], r) + c[0][h][r]);
        float zz = sigf(bfsel(gv[1][h], r) + c[1][h][r]);
        float nn = tanhf_(bfsel(gv[2][h], r) + rr * (c[2][h][r] + bnv));
        hreg[h][r] = (1.f - zz) * nn + zz * hreg[h][r];
      }
    }

    // ---- issue gi loads for t+1 (in flight across pack+barrier+next MFMA) ----
    {
      const __hip_bfloat16* gn = (t + 1 < T) ? gip + gistep : gip;
      gip = gn;
      #pragma unroll
      for (int g = 0; g < 3; ++g)
        #pragma unroll
        for (int h = 0; h < 2; ++h)
          gv[g][h] = *(const uint2*)(gn + g * 256 + h * 16);
    }

    // ---- pack h -> bf16 (round-half-up); store to node + next h-buffer ----
    const int ob0 = bcol * 512 + u0 * 2;
    char* hibn = &hbuf[cur ^ 1][0];
    #pragma unroll
    for (int h = 0; h < 2; ++h) {
      unsigned hb[4];
      #pragma unroll
      for (int r = 0; r < 4; ++r)
        hb[r] = (f2bits(hreg[h][r]) + 0x8000u) & 0xFFFF0000u;
      uint2 hiw;
      hiw.x = (hb[0] >> 16) | hb[1];
      hiw.y = (hb[2] >> 16) | hb[3];
      *(uint2*)(np + h * 16) = hiw;                       // node (fire-and-forget)
      *(uint2*)(hibn + ((ob0 + h * 32) ^ swzh)) = hiw;    // next-step h
    }
    np += nstep;
    asm volatile("s_waitcnt lgkmcnt(0)" ::: "memory");
    __builtin_amdgcn_sched_barrier(0);
    __builtin_amdgcn_s_barrier();
    cur ^= 1;
  }
}

// ---------------- attention over claims (bf16 node, both sides) ----------------
__global__ __launch_bounds__(256) void attn_k(const __hip_bfloat16* nodeAll,
                                              float* wT, float* wS) {
  int b = blockIdx.x, side = blockIdx.y;
  const __hip_bfloat16* node = nodeAll + (long)side * NODE_ELE;
  float* w = side ? wS : wT;
  __shared__ float tl[512];
  __shared__ float sc[CL];
  int tid = threadIdx.x;
  {
    const __hip_bfloat16* tr = node + ((long)b * NNODE + (TL - 1)) * D_;
    tl[tid]       = __bfloat162float(tr[tid]);
    tl[tid + 256] = __bfloat162float(tr[tid + 256]);
  }
  __syncthreads();
  int wid = tid >> 6, lane = tid & 63;
  for (int c = wid; c < CL; c += 4) {
    const __hip_bfloat16* row = node + ((long)b * NNODE + TL + c) * D_;
    uint4 v = *(const uint4*)(row + lane * 8);
    const float* tp = &tl[lane * 8];
    float acc = bits2f(v.x << 16)         * tp[0] + bits2f(v.x & 0xFFFF0000u) * tp[1]
              + bits2f(v.y << 16)         * tp[2] + bits2f(v.y & 0xFFFF0000u) * tp[3]
              + bits2f(v.z << 16)         * tp[4] + bits2f(v.z & 0xFFFF0000u) * tp[5]
              + bits2f(v.w << 16)         * tp[6] + bits2f(v.w & 0xFFFF0000u) * tp[7];
    #pragma unroll
    for (int o = 32; o; o >>= 1) acc += __shfl_xor(acc, o, 64);
    if (lane == 0) sc[c] = acc;
  }
  __syncthreads();
  if (wid == 0) {
    float v[4]; float m = -1e30f;
    #pragma unroll
    for (int i = 0; i < 4; ++i) {
      int c = lane + 64 * i;
      v[i] = (c < CL) ? sc[c] : -1e30f;
      m = fmaxf(m, v[i]);
    }
    #pragma unroll
    for (int o = 32; o; o >>= 1) m = fmaxf(m, __shfl_xor(m, o, 64));
    float s = 0.f;
    #pragma unroll
    for (int i = 0; i < 4; ++i) {
      int c = lane + 64 * i;
      v[i] = (c < CL) ? expf(v[i] - m) : 0.f;
      s += v[i];
    }
    #pragma unroll
    for (int o = 32; o; o >>= 1) s += __shfl_xor(s, o, 64);
    float inv = 1.f / s;
    #pragma unroll
    for (int i = 0; i < 4; ++i) {
      int c = lane + 64 * i;
      if (c < CL) w[(long)b * CL + c] = v[i] * inv;
    }
  }
}

// ---------------- row softmax: f32 in (ld 256, len 250) -> bf16 out, 0-pad ----
__global__ __launch_bounds__(256) void softmaxbf_k(const float* in, __hip_bfloat16* out) {
  int row = blockIdx.x * 4 + (threadIdx.x >> 6);
  int lane = threadIdx.x & 63;
  const float* p = in + (long)row * 256;
  __hip_bfloat16* q = out + (long)row * 256;
  float v[4]; float m = -1e30f;
  #pragma unroll
  for (int i = 0; i < 4; ++i) {
    int c = lane + i * 64;
    v[i] = (c < 250) ? p[c] : -1e30f;
    m = fmaxf(m, v[i]);
  }
  #pragma unroll
  for (int o = 32; o; o >>= 1) m = fmaxf(m, __shfl_xor(m, o, 64));
  float s = 0.f;
  #pragma unroll
  for (int i = 0; i < 4; ++i) {
    int c = lane + i * 64;
    if (c < 250) { v[i] = __expf(v[i] - m); s += v[i]; }
  }
  #pragma unroll
  for (int o = 32; o; o >>= 1) s += __shfl_xor(s, o, 64);
  float inv = 1.f / s;
  #pragma unroll
  for (int i = 0; i < 4; ++i) {
    int c = lane + i * 64;
    q[c] = __float2bfloat16((c < 250) ? v[i] * inv : 0.f);
  }
}

// ---------------- weighted claim pooling (bf16 node, both sides) ----------------
__global__ __launch_bounds__(256) void rep_k(const __hip_bfloat16* nodeAll,
                                             const float* wT, const float* wS,
                                             float* rep) {
  int b = blockIdx.x, side = blockIdx.y;
  const __hip_bfloat16* node = nodeAll + (long)side * NODE_ELE;
  const float* w = side ? wS : wT;
  __shared__ float wl[CL];
  int tid = threadIdx.x;
  if (tid < CL) wl[tid] = w[(long)b * CL + tid];
  __syncthreads();
  #pragma unroll
  for (int h = 0; h < 2; ++h) {
    int d = tid + h * 256;
    float acc = 0.f;
    for (int c = 0; c < CL; ++c)
      acc = fmaf(wl[c], __bfloat162float(node[((long)b * NNODE + TL + c) * D_ + d]), acc);
    rep[((long)side * B_ + b) * D_ + d] = acc;
  }
}

// ---------------- final linear ----------------
__global__ __launch_bounds__(256) void final_k(const float* rep, const float* linW,
                                               const float* linb, float* out) {
  int b = blockIdx.x, tid = threadIdx.x;
  float a0 = 0.f, a1 = 0.f, a2 = 0.f;
  for (int d = tid; d < 1024; d += 256) {
    float x = rep[(long)(d >> 9) * (B_ * D_) + (long)b * D_ + (d & 511)];
    a0 = fmaf(x, linW[d], a0);
    a1 = fmaf(x, linW[1024 + d], a1);
    a2 = fmaf(x, linW[2048 + d], a2);
  }
  #pragma unroll
  for (int o = 32; o; o >>= 1) {
    a0 += __shfl_xor(a0, o, 64);
    a1 += __shfl_xor(a1, o, 64);
    a2 += __shfl_xor(a2, o, 64);
  }
  __shared__ float red[3][4];
  int wid = tid >> 6, lane = tid & 63;
  if (lane == 0) { red[0][wid] = a0; red[1][wid] = a1; red[2][wid] = a2; }
  __syncthreads();
  if (tid == 0) {
    out[b * 3 + 0] = red[0][0] + red[0][1] + red[0][2] + red[0][3] + linb[0];
    out[b * 3 + 1] = red[1][0] + red[1][1] + red[1][2] + red[1][3] + linb[1];
    out[b * 3 + 2] = red[2][0] + red[2][1] + red[2][2] + red[2][3] + linb[2];
  }
}

// ---------------- diagnostic ----------------
__global__ void diag_k(float* out, int n, float v) {
  int i = blockIdx.x * blockDim.x + threadIdx.x;
  if (i < n) out[i] = v;
}

} // namespace

extern "C" void kernel_launch(void* const* d_in, const int* in_sizes, int n_in,
                              void* d_out, int out_size, void* d_ws, size_t ws_size,
                              hipStream_t stream) {
  const int* task_target   = (const int*)d_in[1];
  const int* shared_target = (const int*)d_in[2];
  const int* task_claim    = (const int*)d_in[3];
  const int* shared_claim  = (const int*)d_in[4];
  const float* emb      = (const float*)d_in[9];
  const float* tgt_wih  = (const float*)d_in[10];
  const float* tgt_whh  = (const float*)d_in[11];
  const float* tgt_bih  = (const float*)d_in[12];
  const float* tgt_bhh  = (const float*)d_in[13];
  const float* tgc_wih  = (const float*)d_in[14];
  const float* tgc_whh  = (const float*)d_in[15];
  const float* tgc_bih  = (const float*)d_in[16];
  const float* tgc_bhh  = (const float*)d_in[17];
  const float* sgt_wih  = (const float*)d_in[18];
  const float* sgt_whh  = (const float*)d_in[19];
  const float* sgt_bih  = (const float*)d_in[20];
  const float* sgt_bhh  = (const float*)d_in[21];
  const float* sgc_wih  = (const float*)d_in[22];
  const float* sgc_whh  = (const float*)d_in[23];
  const float* sgc_bih  = (const float*)d_in[24];
  const float* sgc_bhh  = (const float*)d_in[25];
  const float* gcnW_task   = (const float*)d_in[26];
  const float* gcnW_shared = (const float*)d_in[27];
  const float* linW = (const float*)d_in[28];
  const float* linb = (const float*)d_in[29];
  float* out = (float*)d_out;

  // ---- workspace plan (bytes); total ~268.1 MB <= 256 MiB ----
  const size_t SZ_WHH   = 3145728;
  const size_t SZ_GCNW  = 2097152;
  const size_t SZ_BIASC = 24576;
  const size_t SZ_ARENA = 196608000;    // gi all 4 (phase A) / GCN scratch (phase B)
  const size_t SZ_NODE  = 65536000;     // 2 sides x 128x250x512 bf16
  const size_t SZ_W     = 102400;
  const size_t SZ_REP   = 524288;
  const size_t NEED = SZ_WHH + SZ_GCNW + SZ_BIASC + SZ_ARENA + SZ_NODE
                      + 2 * SZ_W + SZ_REP + 4096;

  if (ws_size < NEED) {
    diag_k<<<(out_size + 255) / 256, 256, 0, stream>>>(out, out_size,
                                                       (float)(ws_size >> 20));
    return;
  }

  char* p = (char*)d_ws;
  auto alloc = [&](size_t bytes) { char* r = p; p += (bytes + 255) & ~(size_t)255; return r; };
  __hip_bfloat16* whhbf  = (__hip_bfloat16*)alloc(SZ_WHH);
  __hip_bfloat16* gcnWbf = (__hip_bfloat16*)alloc(SZ_GCNW);   // [side][layer][512][512]
  float* biasC = (float*)alloc(SZ_BIASC);                     // [4][2][768]
  char* arena  = alloc(SZ_ARENA);
  char* nodeC  = alloc(SZ_NODE);
  float* wT    = (float*)alloc(SZ_W);
  float* wS    = (float*)alloc(SZ_W);
  float* rep   = (float*)alloc(SZ_REP);
  __hip_bfloat16* nodebf = (__hip_bfloat16*)nodeC;

  // phase-A views: gi for all 4 GRUs in arena; emb/wih conversions alias nodebf
  __hip_bfloat16* gi_tt = (__hip_bfloat16*)(arena);
  __hip_bfloat16* gi_tc = (__hip_bfloat16*)(arena + 19660800);
  __hip_bfloat16* gi_st = (__hip_bfloat16*)(arena + 98304000);
  __hip_bfloat16* gi_sc = (__hip_bfloat16*)(arena + 117964800);
  __hip_bfloat16* embbf = (__hip_bfloat16*)(nodeC);                  // [30000][320]
  __hip_bfloat16* wihbf[4] = {                                       // [2][768][320] each
    (__hip_bfloat16*)(nodeC + 19200000),
    (__hip_bfloat16*)(nodeC + 20183040),
    (__hip_bfloat16*)(nodeC + 21166080),
    (__hip_bfloat16*)(nodeC + 22149120)};
  // phase-B (GCN) views of arena, both sides fused (z = 0..255)
  __hip_bfloat16* tmpbf  = (__hip_bfloat16*)(arena);                 // [256][250][512]
  __hip_bfloat16* corrbf = (__hip_bfloat16*)(arena + 65536000);      // [256][250][256]
  float*          corrF  = (float*)(arena + 98304000);               // [256][250][256] f32
  __hip_bfloat16* transT = (__hip_bfloat16*)(arena + 98304000);      // aliases corrF (dead)

  // ---- fused prep (1 dispatch) ----
  {
    PrepArgs pa;
    pa.whh[0] = tgt_whh; pa.whh[1] = tgc_whh; pa.whh[2] = sgt_whh; pa.whh[3] = sgc_whh;
    pa.gcnW[0] = gcnW_task; pa.gcnW[1] = gcnW_shared;
    pa.emb = emb;
    pa.wih[0] = tgt_wih; pa.wih[1] = tgc_wih; pa.wih[2] = sgt_wih; pa.wih[3] = sgc_wih;
    pa.bih[0] = tgt_bih; pa.bih[1] = tgc_bih; pa.bih[2] = sgt_bih; pa.bih[3] = sgc_bih;
    pa.bhh[0] = tgt_bhh; pa.bhh[1] = tgc_bhh; pa.bhh[2] = sgt_bhh; pa.bhh[3] = sgc_bhh;
    pa.whhbf = whhbf; pa.gcnWbf = gcnWbf; pa.embbf = embbf;
    pa.wihbf[0] = wihbf[0]; pa.wihbf[1] = wihbf[1];
    pa.wihbf[2] = wihbf[2]; pa.wihbf[3] = wihbf[3];
    pa.biasC = biasC;
    prep_k<<<(int)((PR4 + 255) / 256), 256, 0, stream>>>(pa);
  }

  // ---- projections: gi = emb[tok] @ Wih^T + biasC (bf16), K padded to 320 ----
  auto proj = [&](const int* idx, __hip_bfloat16* wih, const float* bias,
                  __hip_bfloat16* gi, int Mrows, int gx) {
    BGemmArgs ga{};
    ga.A = embbf; ga.idx = idx; ga.B = wih; ga.bias = bias; ga.C = gi;
    ga.aStride = 0; ga.bStride = 768L * 320; ga.biasStride = 768;
    ga.cStride = (long)Mrows * 768; ga.zShiftA = 0;
    ga.M = Mrows; ga.N = 768; ga.Kreal = 320; ga.lda = 320; ga.ldb = 320; ga.ldc = 768;
    bgemm_k<true, 1><<<dim3(gx, 6, 2), 256, 0, stream>>>(ga);
  };
  proj(task_target,   wihbf[0], biasC,        gi_tt, 6400, 50);
  proj(task_claim,    wihbf[1], biasC + 1536, gi_tc, 25600, 200);
  proj(shared_target, wihbf[2], biasC + 3072, gi_st, 6400, 50);
  proj(shared_claim,  wihbf[3], biasC + 4608, gi_sc, 25600, 200);

  // ---- all 8 GRU chains in ONE dispatch (writes nodebf over emb/wih alias) ----
  RecArgs ra;
  ra.whhbf = whhbf;
  ra.gi[0] = gi_tt; ra.gi[1] = gi_tc; ra.gi[2] = gi_st; ra.gi[3] = gi_sc;
  ra.bhh[0] = tgt_bhh; ra.bhh[1] = tgc_bhh; ra.bhh[2] = sgt_bhh; ra.bhh[3] = sgc_bhh;
  ra.nodebf = nodebf;
  gru_rec_k<<<dim3(8, 1, 8), 512, 0, stream>>>(ra);

  // ---- stance attention, both sides ----
  attn_k<<<dim3(128, 2), 256, 0, stream>>>(nodebf, wT, wS);

  // ---- GCN 2 layers, BOTH sides fused (z = 0..255; side = z>>7) ----
  for (int layer = 0; layer < 2; ++layer) {
    const __hip_bfloat16* inbf = layer ? tmpbf : nodebf;   // z-contiguous across sides
    BGemmArgs ca{};   // corr = in @ in^T (f32)
    ca.A = inbf; ca.B = inbf; ca.C = corrF;
    ca.aStride = 128000; ca.bStride = 128000; ca.cStride = 64000; ca.zShiftA = 0;
    ca.M = 250; ca.N = 250; ca.Kreal = 512; ca.lda = 512; ca.ldb = 512; ca.ldc = 256;
    bgemm_k<false, 0><<<dim3(2, 2, 256), 256, 0, stream>>>(ca);
    softmaxbf_k<<<16000, 256, 0, stream>>>(corrF, corrbf);
    BGemmArgs ta{};   // trans^T = W[side] @ in^T (bf16, 0-pad cols 250..255)
    ta.A = gcnWbf + (long)layer * 262144; ta.B = inbf; ta.C = transT;
    ta.aStride = 524288; ta.bStride = 128000; ta.cStride = 131072; ta.zShiftA = 7;
    ta.M = 512; ta.N = 250; ta.Kreal = 512; ta.lda = 512; ta.ldb = 512; ta.ldc = 256;
    bgemm_k<false, 3><<<dim3(4, 2, 256), 256, 0, stream>>>(ta);
    BGemmArgs aa{};   // out = relu(res + corr @ trans), all bf16
    aa.A = corrbf; aa.B = transT; aa.Res = inbf;
    aa.C = layer ? (void*)nodebf : (void*)tmpbf;
    aa.aStride = 64000; aa.bStride = 131072; aa.cStride = 128000;
    aa.rStride = 128000; aa.zShiftA = 0;
    aa.M = 250; aa.N = 512; aa.Kreal = 256; aa.lda = 256; aa.ldb = 256; aa.ldc = 512;
    bgemm_k<false, 5><<<dim3(2, 4, 256), 256, 0, stream>>>(aa);
  }

  // ---- pooling (post-GCN node in nodebf), final linear ----
  rep_k<<<dim3(128, 2), 256, 0, stream>>>(nodebf, wT, wS, rep);
  final_k<<<dim3(128), 256, 0, stream>>>(rep, linW, linb, out);
}

// Round 15
// 1511.296 us; speedup vs baseline: 1.2500x; 1.0107x over previous
//
#include <hip/hip_runtime.h>
#include <hip/hip_bf16.h>

namespace {

constexpr int B_  = 128;
constexpr int TL  = 50, CL = 200, NNODE = 250;
constexpr int H_  = 256, D_ = 512;
constexpr long NODE_ELE = 128L * 250 * 512;   // per side

typedef __attribute__((ext_vector_type(8))) short bf16x8;
typedef __attribute__((ext_vector_type(4))) float f32x4;

__device__ inline float bits2f(unsigned v) { union { unsigned u; float f; } c; c.u = v; return c.f; }
__device__ inline unsigned f2bits(float x) { union { float f; unsigned u; } c; c.f = x; return c.u; }
__device__ inline unsigned short bfbits(float x) {
  __hip_bfloat16 b = __float2bfloat16(x);
  return *(unsigned short*)&b;
}
__device__ inline float bfsel(uint2 v, int r) {        // r-th bf16 of a 4-pack
  unsigned w = (r < 2) ? v.x : v.y;
  return bits2f((r & 1) ? (w & 0xFFFF0000u) : (w << 16));
}
__device__ inline float sigf(float x)  { return 1.f / (1.f + __expf(-x)); }
__device__ inline float tanhf_(float x){ return 1.f - 2.f / (__expf(2.f * x) + 1.f); }

// =============== bf16 MFMA GEMM: C[z] = A[za] @ B[z]^T (B is [N][K]) ==========
// global_load_lds 16B staging, double-buffered (R14). K % 64 == 0 required.
// OUT modes: 1: +bias -> bf16. 3: bf16 out, zero-fill cols [N,256).
// 5: +bf16 Res, relu -> bf16 out.
struct BGemmArgs {
  const __hip_bfloat16* A; const __hip_bfloat16* B;
  const int* idx; const float* bias; const __hip_bfloat16* Res;
  void* C;
  long aStride, bStride, biasStride, cStride, rStride;
  int M, N, Kreal, lda, ldb, ldc, zShiftA;
};

template<bool GATHER, int OUT>
__global__ __launch_bounds__(256) void bgemm_k(BGemmArgs g) {
  __shared__ __align__(16) char As[2][16384];   // [buf][128 rows][64 k] bf16 linear
  __shared__ __align__(16) char Bs[2][16384];
  const int z = blockIdx.z;
  const int m0 = blockIdx.x * 128, n0 = blockIdx.y * 128;
  const int tid = threadIdx.x;
  const int lane = tid & 63, wv = tid >> 6;
  const int wr = wv >> 1, wc = wv & 1;                    // wave -> 64x64 quadrant
  const __hip_bfloat16* Ab = GATHER ? g.A : g.A + (long)(z >> g.zShiftA) * g.aStride;
  const __hip_bfloat16* Bb = g.B + (long)z * g.bStride;

  long asrc[4], bsrc[4];
  int ldso[4];
  #pragma unroll
  for (int c2 = 0; c2 < 4; ++c2) {
    int o = c2 * 256 + tid;
    int row = o >> 3, ko = o & 7;
    int colel = 8 * (ko ^ (row & 7));
    long arow = GATHER ? (long)g.idx[m0 + row] * g.lda : (long)(m0 + row) * g.lda;
    asrc[c2] = arow + colel;
    bsrc[c2] = (long)(n0 + row) * g.ldb + colel;
    ldso[c2] = o * 16;
  }

  f32x4 acc[4][4];
  #pragma unroll
  for (int i = 0; i < 4; ++i)
    #pragma unroll
    for (int j = 0; j < 4; ++j) acc[i][j] = (f32x4){0.f, 0.f, 0.f, 0.f};

  const int KT = g.Kreal >> 6;
  #pragma unroll
  for (int c2 = 0; c2 < 4; ++c2) {
    __builtin_amdgcn_global_load_lds(
        (const __attribute__((address_space(1))) unsigned*)(Ab + asrc[c2]),
        (__attribute__((address_space(3))) unsigned*)(&As[0][0] + ldso[c2]), 16, 0, 0);
    __builtin_amdgcn_global_load_lds(
        (const __attribute__((address_space(1))) unsigned*)(Bb + bsrc[c2]),
        (__attribute__((address_space(3))) unsigned*)(&Bs[0][0] + ldso[c2]), 16, 0, 0);
  }
  __syncthreads();

  int buf = 0;
  for (int kt = 0; kt < KT; ++kt) {
    if (kt + 1 < KT) {
      long ko = (long)(kt + 1) * 64;
      #pragma unroll
      for (int c2 = 0; c2 < 4; ++c2) {
        __builtin_amdgcn_global_load_lds(
            (const __attribute__((address_space(1))) unsigned*)(Ab + asrc[c2] + ko),
            (__attribute__((address_space(3))) unsigned*)(&As[buf ^ 1][0] + ldso[c2]), 16, 0, 0);
        __builtin_amdgcn_global_load_lds(
            (const __attribute__((address_space(1))) unsigned*)(Bb + bsrc[c2] + ko),
            (__attribute__((address_space(3))) unsigned*)(&Bs[buf ^ 1][0] + ldso[c2]), 16, 0, 0);
      }
    }
    const char* ab = &As[buf][0];
    const char* bb = &Bs[buf][0];
    #pragma unroll
    for (int ks = 0; ks < 2; ++ks) {
      bf16x8 af[4], bfr[4];
      #pragma unroll
      for (int i = 0; i < 4; ++i) {
        int ra = wr * 64 + i * 16 + (lane & 15);
        af[i] = *(const bf16x8*)(ab + ((ra * 128 + ks * 64 + (lane >> 4) * 16) ^ ((ra & 7) << 4)));
        int rb = wc * 64 + i * 16 + (lane & 15);
        bfr[i] = *(const bf16x8*)(bb + ((rb * 128 + ks * 64 + (lane >> 4) * 16) ^ ((rb & 7) << 4)));
      }
      #pragma unroll
      for (int i = 0; i < 4; ++i)
        #pragma unroll
        for (int j = 0; j < 4; ++j)
          acc[i][j] = __builtin_amdgcn_mfma_f32_16x16x32_bf16(af[i], bfr[j], acc[i][j], 0, 0, 0);
    }
    __syncthreads();
    buf ^= 1;
  }

  const long cz = (long)z * g.cStride;
  #pragma unroll
  for (int i = 0; i < 4; ++i) {
    int rbase = m0 + wr * 64 + i * 16 + ((lane >> 4) << 2);
    #pragma unroll
    for (int j = 0; j < 4; ++j) {
      int col = n0 + wc * 64 + j * 16 + (lane & 15);
      #pragma unroll
      for (int r = 0; r < 4; ++r) {
        int row = rbase + r;
        float v = acc[i][j][r];
        if (OUT == 1) {
          if (row < g.M && col < g.N) {
            v += g.bias[(long)z * g.biasStride + col];
            ((__hip_bfloat16*)g.C)[cz + (long)row * g.ldc + col] = __float2bfloat16(v);
          }
        } else if (OUT == 3) {
          if (row < g.M)
            ((__hip_bfloat16*)g.C)[cz + (long)row * g.ldc + col] =
                __float2bfloat16(col < g.N ? v : 0.f);
        } else {  // OUT == 5
          if (row < g.M && col < g.N) {
            v += __bfloat162float(g.Res[(long)z * g.rStride + (long)row * g.ldc + col]);
            v = fmaxf(v, 0.f);
            ((__hip_bfloat16*)g.C)[cz + (long)row * g.ldc + col] = __float2bfloat16(v);
          }
        }
      }
    }
  }
}

// ====== fused corr+softmax: out[z] = softmax_row(in[z] @ in[z]^T), bf16 =======
// M-tile 64 x N-tile 256: each wave owns 16 FULL rows -> in-register row
// softmax (shfl_xor over the 16-lane column group). Cols >= 250 masked and
// written 0. Same staging pattern as bgemm_k. K = 512 fixed.
struct CsmArgs { const __hip_bfloat16* in; __hip_bfloat16* outp; };

__global__ __launch_bounds__(256) void csm_k(CsmArgs g) {
  __shared__ __align__(16) char As[2][8192];    // 64 rows x 64 k
  __shared__ __align__(16) char Bs[2][32768];   // 256 rows x 64 k
  const int z = blockIdx.z;
  const int m0 = blockIdx.x * 64;
  const int tid = threadIdx.x;
  const int lane = tid & 63, wv = tid >> 6;
  const __hip_bfloat16* base = g.in + (long)z * 128000;

  long bsrc[8]; int bo[8];
  #pragma unroll
  for (int c2 = 0; c2 < 8; ++c2) {
    int o = c2 * 256 + tid;
    int row = o >> 3, ko = o & 7;
    bsrc[c2] = (long)row * 512 + 8 * (ko ^ (row & 7));
    bo[c2] = o * 16;
  }
  long asrc[2]; int ao[2];
  #pragma unroll
  for (int c2 = 0; c2 < 2; ++c2) {
    int o = c2 * 256 + tid;
    int row = o >> 3, ko = o & 7;
    asrc[c2] = (long)(m0 + row) * 512 + 8 * (ko ^ (row & 7));
    ao[c2] = o * 16;
  }

  f32x4 acc[16];
  #pragma unroll
  for (int j = 0; j < 16; ++j) acc[j] = (f32x4){0.f, 0.f, 0.f, 0.f};

  // prologue: stage k-tile 0
  #pragma unroll
  for (int c2 = 0; c2 < 2; ++c2)
    __builtin_amdgcn_global_load_lds(
        (const __attribute__((address_space(1))) unsigned*)(base + asrc[c2]),
        (__attribute__((address_space(3))) unsigned*)(&As[0][0] + ao[c2]), 16, 0, 0);
  #pragma unroll
  for (int c2 = 0; c2 < 8; ++c2)
    __builtin_amdgcn_global_load_lds(
        (const __attribute__((address_space(1))) unsigned*)(base + bsrc[c2]),
        (__attribute__((address_space(3))) unsigned*)(&Bs[0][0] + bo[c2]), 16, 0, 0);
  __syncthreads();

  int buf = 0;
  for (int kt = 0; kt < 8; ++kt) {
    if (kt + 1 < 8) {
      long ko = (long)(kt + 1) * 64;
      #pragma unroll
      for (int c2 = 0; c2 < 2; ++c2)
        __builtin_amdgcn_global_load_lds(
            (const __attribute__((address_space(1))) unsigned*)(base + asrc[c2] + ko),
            (__attribute__((address_space(3))) unsigned*)(&As[buf ^ 1][0] + ao[c2]), 16, 0, 0);
      #pragma unroll
      for (int c2 = 0; c2 < 8; ++c2)
        __builtin_amdgcn_global_load_lds(
            (const __attribute__((address_space(1))) unsigned*)(base + bsrc[c2] + ko),
            (__attribute__((address_space(3))) unsigned*)(&Bs[buf ^ 1][0] + bo[c2]), 16, 0, 0);
    }
    const char* ab = &As[buf][0];
    const char* bb = &Bs[buf][0];
    #pragma unroll
    for (int ks = 0; ks < 2; ++ks) {
      int ra = wv * 16 + (lane & 15);
      bf16x8 af = *(const bf16x8*)(ab + ((ra * 128 + ks * 64 + (lane >> 4) * 16) ^ ((ra & 7) << 4)));
      #pragma unroll
      for (int j = 0; j < 16; ++j) {
        int rb = j * 16 + (lane & 15);
        bf16x8 bf = *(const bf16x8*)(bb + ((rb * 128 + ks * 64 + (lane >> 4) * 16) ^ ((rb & 7) << 4)));
        acc[j] = __builtin_amdgcn_mfma_f32_16x16x32_bf16(af, bf, acc[j], 0, 0, 0);
      }
    }
    __syncthreads();
    buf ^= 1;
  }

  // ---- epilogue: per-row softmax in-register, write bf16 (0-pad >=250) ----
  const int c0 = lane & 15, rq = lane >> 4;
  const long obase = (long)z * 64000;
  #pragma unroll
  for (int r = 0; r < 4; ++r) {
    int row = m0 + wv * 16 + rq * 4 + r;
    float vals[16];
    float mx = -1e30f;
    #pragma unroll
    for (int j = 0; j < 16; ++j) {
      vals[j] = acc[j][r];
      if (j * 16 + c0 < 250) mx = fmaxf(mx, vals[j]);
    }
    #pragma unroll
    for (int o = 1; o < 16; o <<= 1) mx = fmaxf(mx, __shfl_xor(mx, o, 64));
    float s = 0.f;
    #pragma unroll
    for (int j = 0; j < 16; ++j) {
      float e = (j * 16 + c0 < 250) ? __expf(vals[j] - mx) : 0.f;
      vals[j] = e; s += e;
    }
    #pragma unroll
    for (int o = 1; o < 16; o <<= 1) s += __shfl_xor(s, o, 64);
    float inv = 1.f / s;
    if (row < 250) {
      #pragma unroll
      for (int j = 0; j < 16; ++j)
        g.outp[obase + (long)row * 256 + j * 16 + c0] = __float2bfloat16(vals[j] * inv);
    }
  }
}

// ---------------- fused prep: whh/gcnW/emb/wih -> bf16(+pad 320), biasC -------
struct PrepArgs {
  const float* whh[4];
  const float* gcnW[2];
  const float* emb;
  const float* wih[4];
  const float* bih[4];
  const float* bhh[4];
  __hip_bfloat16 *whhbf, *gcnWbf, *embbf;
  __hip_bfloat16* wihbf[4];
  float* biasC;
};

constexpr long PR0 = 1572864;
constexpr long PR1 = PR0 + 1048576;
constexpr long PR2 = PR1 + 9600000;
constexpr long PR3 = PR2 + 1966080;
constexpr long PR4 = PR3 + 6144;

__global__ __launch_bounds__(256) void prep_k(PrepArgs a) {
  long i = (long)blockIdx.x * 256 + threadIdx.x;
  if (i >= PR4) return;
  if (i < PR0) {
    int zz = (int)(i / 196608);
    long rem = i - (long)zz * 196608;
    a.whhbf[i] = __float2bfloat16(a.whh[zz >> 1][(long)(zz & 1) * 196608 + rem]);
  } else if (i < PR1) {
    long j = i - PR0;
    a.gcnWbf[j] = __float2bfloat16(a.gcnW[j / 524288][j % 524288]);
  } else if (i < PR2) {
    long j = i - PR1;
    long r = j / 320;
    int c = (int)(j - r * 320);
    a.embbf[j] = __float2bfloat16(c < 300 ? a.emb[r * 300 + c] : 0.f);
  } else if (i < PR3) {
    long j = i - PR2;
    int w = (int)(j / 491520);
    long k = j - (long)w * 491520;
    long r = k / 320;
    int c = (int)(k - r * 320);
    a.wihbf[w][k] = __float2bfloat16(c < 300 ? a.wih[w][r * 300 + c] : 0.f);
  } else {
    long j = i - PR3;
    int w = (int)(j / 1536);
    int k = (int)(j - (long)w * 1536);
    a.biasC[(long)w * 1536 + k] = a.bih[w][k] + ((k % 768) < 512 ? a.bhh[w][k] : 0.f);
  }
}

// ---------------- GRU recurrence (R13 structure, measured floor ~802us) ------
struct RecArgs {
  const __hip_bfloat16* whhbf;
  const __hip_bfloat16* gi[4];
  const float* bhh[4];
  __hip_bfloat16* nodebf;
};

__global__ __launch_bounds__(512, 2) void gru_rec_k(RecArgs a) {
  __shared__ __align__(16) char hbuf[2][8192];
  const int z = blockIdx.z;
  const int side = z >> 2, sq = (z >> 1) & 1, dir = z & 1;
  const int gidx = side * 2 + sq;
  const int T = sq ? CL : TL;
  const int toff = sq ? TL : 0;
  const __hip_bfloat16* gi = a.gi[gidx] + (long)dir * B_ * T * 768;
  const float* bhh = a.bhh[gidx] + dir * 768;
  const __hip_bfloat16* whh = a.whhbf + (long)z * 768 * 256;
  __hip_bfloat16* nodeb = a.nodebf + (long)side * NODE_ELE;
  const int b0 = blockIdx.x * 16;
  const int tid = threadIdx.x;
  const int lane = tid & 63, wv = tid >> 6;
  const int bcol = lane & 15, g4 = lane >> 4;
  const int u0 = wv * 32 + g4 * 4;
  const int swzh = (bcol & 15) << 4;

  bf16x8 Af[3][2][8];
  #pragma unroll
  for (int g = 0; g < 3; ++g)
    #pragma unroll
    for (int h = 0; h < 2; ++h)
      #pragma unroll
      for (int kt = 0; kt < 8; ++kt) {
        int row = g * 256 + wv * 32 + h * 16 + bcol;
        int col = kt * 32 + g4 * 8;
        Af[g][h][kt] = *(const bf16x8*)(whh + (long)row * 256 + col);
      }
  *(uint4*)&hbuf[0][tid * 16] = make_uint4(0, 0, 0, 0);
  const float4 bn0 = *(const float4*)&bhh[512 + u0];
  const float4 bn1 = *(const float4*)&bhh[512 + u0 + 16];
  __syncthreads();

  const __hip_bfloat16* gip = gi + ((long)(b0 + bcol) * T + (dir ? T - 1 : 0)) * 768 + u0;
  __hip_bfloat16* np = nodeb + ((long)(b0 + bcol) * NNODE + toff + (dir ? T - 1 : 0)) * D_
                       + dir * H_ + u0;
  const long gistep = dir ? -768L : 768L;
  const long nstep  = dir ? -(long)D_ : (long)D_;
  int cur = 0;

  float hreg[2][4];
  #pragma unroll
  for (int h = 0; h < 2; ++h)
    #pragma unroll
    for (int r = 0; r < 4; ++r) hreg[h][r] = 0.f;

  uint2 gv[3][2];
  #pragma unroll
  for (int g = 0; g < 3; ++g)
    #pragma unroll
    for (int h = 0; h < 2; ++h)
      gv[g][h] = *(const uint2*)(gip + g * 256 + h * 16);

  for (int t = 0; t < T; ++t) {
    const char* hib = &hbuf[cur][0];
    f32x4 c[3][2];
    #pragma unroll
    for (int g = 0; g < 3; ++g)
      #pragma unroll
      for (int h = 0; h < 2; ++h) c[g][h] = (f32x4){0.f, 0.f, 0.f, 0.f};
    const int rb = bcol * 512 + g4 * 16;
    #pragma unroll
    for (int kt = 0; kt < 8; ++kt) {
      bf16x8 bh = *(const bf16x8*)(hib + ((rb + kt * 64) ^ swzh));
      #pragma unroll
      for (int g = 0; g < 3; ++g)
        #pragma unroll
        for (int h = 0; h < 2; ++h)
          c[g][h] = __builtin_amdgcn_mfma_f32_16x16x32_bf16(Af[g][h][kt], bh, c[g][h], 0, 0, 0);
    }

    #pragma unroll
    for (int h = 0; h < 2; ++h) {
      float4 bn = h ? bn1 : bn0;
      #pragma unroll
      for (int r = 0; r < 4; ++r) {
        float bnv = (r == 0) ? bn.x : (r == 1) ? bn.y : (r == 2) ? bn.z : bn.w;
        float rr = sigf(bfsel(gv[0][h], r) + c[0][h][r]);
        float zz = sigf(bfsel(gv[1][h], r) + c[1][h][r]);
        float nn = tanhf_(bfsel(gv[2][h], r) + rr * (c[2][h][r] + bnv));
        hreg[h][r] = (1.f - zz) * nn + zz * hreg[h][r];
      }
    }

    {
      const __hip_bfloat16* gn = (t + 1 < T) ? gip + gistep : gip;
      gip = gn;
      #pragma unroll
      for (int g = 0; g < 3; ++g)
        #pragma unroll
        for (int h = 0; h < 2; ++h)
          gv[g][h] = *(const uint2*)(gn + g * 256 + h * 16);
    }

    const int ob0 = bcol * 512 + u0 * 2;
    char* hibn = &hbuf[cur ^ 1][0];
    #pragma unroll
    for (int h = 0; h < 2; ++h) {
      unsigned hb[4];
      #pragma unroll
      for (int r = 0; r < 4; ++r)
        hb[r] = (f2bits(hreg[h][r]) + 0x8000u) & 0xFFFF0000u;
      uint2 hiw;
      hiw.x = (hb[0] >> 16) | hb[1];
      hiw.y = (hb[2] >> 16) | hb[3];
      *(uint2*)(np + h * 16) = hiw;
      *(uint2*)(hibn + ((ob0 + h * 32) ^ swzh)) = hiw;
    }
    np += nstep;
    asm volatile("s_waitcnt lgkmcnt(0)" ::: "memory");
    __builtin_amdgcn_sched_barrier(0);
    __builtin_amdgcn_s_barrier();
    cur ^= 1;
  }
}

// ---------------- attention over claims (bf16 node, both sides) ----------------
__global__ __launch_bounds__(256) void attn_k(const __hip_bfloat16* nodeAll,
                                              float* wT, float* wS) {
  int b = blockIdx.x, side = blockIdx.y;
  const __hip_bfloat16* node = nodeAll + (long)side * NODE_ELE;
  float* w = side ? wS : wT;
  __shared__ float tl[512];
  __shared__ float sc[CL];
  int tid = threadIdx.x;
  {
    const __hip_bfloat16* tr = node + ((long)b * NNODE + (TL - 1)) * D_;
    tl[tid]       = __bfloat162float(tr[tid]);
    tl[tid + 256] = __bfloat162float(tr[tid + 256]);
  }
  __syncthreads();
  int wid = tid >> 6, lane = tid & 63;
  for (int c = wid; c < CL; c += 4) {
    const __hip_bfloat16* row = node + ((long)b * NNODE + TL + c) * D_;
    uint4 v = *(const uint4*)(row + lane * 8);
    const float* tp = &tl[lane * 8];
    float acc = bits2f(v.x << 16)         * tp[0] + bits2f(v.x & 0xFFFF0000u) * tp[1]
              + bits2f(v.y << 16)         * tp[2] + bits2f(v.y & 0xFFFF0000u) * tp[3]
              + bits2f(v.z << 16)         * tp[4] + bits2f(v.z & 0xFFFF0000u) * tp[5]
              + bits2f(v.w << 16)         * tp[6] + bits2f(v.w & 0xFFFF0000u) * tp[7];
    #pragma unroll
    for (int o = 32; o; o >>= 1) acc += __shfl_xor(acc, o, 64);
    if (lane == 0) sc[c] = acc;
  }
  __syncthreads();
  if (wid == 0) {
    float v[4]; float m = -1e30f;
    #pragma unroll
    for (int i = 0; i < 4; ++i) {
      int c = lane + 64 * i;
      v[i] = (c < CL) ? sc[c] : -1e30f;
      m = fmaxf(m, v[i]);
    }
    #pragma unroll
    for (int o = 32; o; o >>= 1) m = fmaxf(m, __shfl_xor(m, o, 64));
    float s = 0.f;
    #pragma unroll
    for (int i = 0; i < 4; ++i) {
      int c = lane + 64 * i;
      v[i] = (c < CL) ? expf(v[i] - m) : 0.f;
      s += v[i];
    }
    #pragma unroll
    for (int o = 32; o; o >>= 1) s += __shfl_xor(s, o, 64);
    float inv = 1.f / s;
    #pragma unroll
    for (int i = 0; i < 4; ++i) {
      int c = lane + 64 * i;
      if (c < CL) w[(long)b * CL + c] = v[i] * inv;
    }
  }
}

// ---------------- weighted claim pooling (bf16 node, both sides) ----------------
__global__ __launch_bounds__(256) void rep_k(const __hip_bfloat16* nodeAll,
                                             const float* wT, const float* wS,
                                             float* rep) {
  int b = blockIdx.x, side = blockIdx.y;
  const __hip_bfloat16* node = nodeAll + (long)side * NODE_ELE;
  const float* w = side ? wS : wT;
  __shared__ float wl[CL];
  int tid = threadIdx.x;
  if (tid < CL) wl[tid] = w[(long)b * CL + tid];
  __syncthreads();
  #pragma unroll
  for (int h = 0; h < 2; ++h) {
    int d = tid + h * 256;
    float acc = 0.f;
    for (int c = 0; c < CL; ++c)
      acc = fmaf(wl[c], __bfloat162float(node[((long)b * NNODE + TL + c) * D_ + d]), acc);
    rep[((long)side * B_ + b) * D_ + d] = acc;
  }
}

// ---------------- final linear ----------------
__global__ __launch_bounds__(256) void final_k(const float* rep, const float* linW,
                                               const float* linb, float* out) {
  int b = blockIdx.x, tid = threadIdx.x;
  float a0 = 0.f, a1 = 0.f, a2 = 0.f;
  for (int d = tid; d < 1024; d += 256) {
    float x = rep[(long)(d >> 9) * (B_ * D_) + (long)b * D_ + (d & 511)];
    a0 = fmaf(x, linW[d], a0);
    a1 = fmaf(x, linW[1024 + d], a1);
    a2 = fmaf(x, linW[2048 + d], a2);
  }
  #pragma unroll
  for (int o = 32; o; o >>= 1) {
    a0 += __shfl_xor(a0, o, 64);
    a1 += __shfl_xor(a1, o, 64);
    a2 += __shfl_xor(a2, o, 64);
  }
  __shared__ float red[3][4];
  int wid = tid >> 6, lane = tid & 63;
  if (lane == 0) { red[0][wid] = a0; red[1][wid] = a1; red[2][wid] = a2; }
  __syncthreads();
  if (tid == 0) {
    out[b * 3 + 0] = red[0][0] + red[0][1] + red[0][2] + red[0][3] + linb[0];
    out[b * 3 + 1] = red[1][0] + red[1][1] + red[1][2] + red[1][3] + linb[1];
    out[b * 3 + 2] = red[2][0] + red[2][1] + red[2][2] + red[2][3] + linb[2];
  }
}

// ---------------- diagnostic ----------------
__global__ void diag_k(float* out, int n, float v) {
  int i = blockIdx.x * blockDim.x + threadIdx.x;
  if (i < n) out[i] = v;
}

} // namespace

extern "C" void kernel_launch(void* const* d_in, const int* in_sizes, int n_in,
                              void* d_out, int out_size, void* d_ws, size_t ws_size,
                              hipStream_t stream) {
  const int* task_target   = (const int*)d_in[1];
  const int* shared_target = (const int*)d_in[2];
  const int* task_claim    = (const int*)d_in[3];
  const int* shared_claim  = (const int*)d_in[4];
  const float* emb      = (const float*)d_in[9];
  const float* tgt_wih  = (const float*)d_in[10];
  const float* tgt_whh  = (const float*)d_in[11];
  const float* tgt_bih  = (const float*)d_in[12];
  const float* tgt_bhh  = (const float*)d_in[13];
  const float* tgc_wih  = (const float*)d_in[14];
  const float* tgc_whh  = (const float*)d_in[15];
  const float* tgc_bih  = (const float*)d_in[16];
  const float* tgc_bhh  = (const float*)d_in[17];
  const float* sgt_wih  = (const float*)d_in[18];
  const float* sgt_whh  = (const float*)d_in[19];
  const float* sgt_bih  = (const float*)d_in[20];
  const float* sgt_bhh  = (const float*)d_in[21];
  const float* sgc_wih  = (const float*)d_in[22];
  const float* sgc_whh  = (const float*)d_in[23];
  const float* sgc_bih  = (const float*)d_in[24];
  const float* sgc_bhh  = (const float*)d_in[25];
  const float* gcnW_task   = (const float*)d_in[26];
  const float* gcnW_shared = (const float*)d_in[27];
  const float* linW = (const float*)d_in[28];
  const float* linb = (const float*)d_in[29];
  float* out = (float*)d_out;

  const size_t SZ_WHH   = 3145728;
  const size_t SZ_GCNW  = 2097152;
  const size_t SZ_BIASC = 24576;
  const size_t SZ_ARENA = 196608000;
  const size_t SZ_NODE  = 65536000;
  const size_t SZ_W     = 102400;
  const size_t SZ_REP   = 524288;
  const size_t NEED = SZ_WHH + SZ_GCNW + SZ_BIASC + SZ_ARENA + SZ_NODE
                      + 2 * SZ_W + SZ_REP + 4096;

  if (ws_size < NEED) {
    diag_k<<<(out_size + 255) / 256, 256, 0, stream>>>(out, out_size,
                                                       (float)(ws_size >> 20));
    return;
  }

  char* p = (char*)d_ws;
  auto alloc = [&](size_t bytes) { char* r = p; p += (bytes + 255) & ~(size_t)255; return r; };
  __hip_bfloat16* whhbf  = (__hip_bfloat16*)alloc(SZ_WHH);
  __hip_bfloat16* gcnWbf = (__hip_bfloat16*)alloc(SZ_GCNW);
  float* biasC = (float*)alloc(SZ_BIASC);
  char* arena  = alloc(SZ_ARENA);
  char* nodeC  = alloc(SZ_NODE);
  float* wT    = (float*)alloc(SZ_W);
  float* wS    = (float*)alloc(SZ_W);
  float* rep   = (float*)alloc(SZ_REP);
  __hip_bfloat16* nodebf = (__hip_bfloat16*)nodeC;

  // phase-A views
  __hip_bfloat16* gi_tt = (__hip_bfloat16*)(arena);
  __hip_bfloat16* gi_tc = (__hip_bfloat16*)(arena + 19660800);
  __hip_bfloat16* gi_st = (__hip_bfloat16*)(arena + 98304000);
  __hip_bfloat16* gi_sc = (__hip_bfloat16*)(arena + 117964800);
  __hip_bfloat16* embbf = (__hip_bfloat16*)(nodeC);                  // [30000][320]
  __hip_bfloat16* wihbf[4] = {
    (__hip_bfloat16*)(nodeC + 19200000),
    (__hip_bfloat16*)(nodeC + 20183040),
    (__hip_bfloat16*)(nodeC + 21166080),
    (__hip_bfloat16*)(nodeC + 22149120)};
  // phase-B views: tmpbf | corrbf | transT (corrF eliminated)
  __hip_bfloat16* tmpbf  = (__hip_bfloat16*)(arena);                 // [256][250][512]
  __hip_bfloat16* corrbf = (__hip_bfloat16*)(arena + 65536000);      // [256][250][256]
  __hip_bfloat16* transT = (__hip_bfloat16*)(arena + 98304000);      // [256][512][256]

  // ---- fused prep ----
  {
    PrepArgs pa;
    pa.whh[0] = tgt_whh; pa.whh[1] = tgc_whh; pa.whh[2] = sgt_whh; pa.whh[3] = sgc_whh;
    pa.gcnW[0] = gcnW_task; pa.gcnW[1] = gcnW_shared;
    pa.emb = emb;
    pa.wih[0] = tgt_wih; pa.wih[1] = tgc_wih; pa.wih[2] = sgt_wih; pa.wih[3] = sgc_wih;
    pa.bih[0] = tgt_bih; pa.bih[1] = tgc_bih; pa.bih[2] = sgt_bih; pa.bih[3] = sgc_bih;
    pa.bhh[0] = tgt_bhh; pa.bhh[1] = tgc_bhh; pa.bhh[2] = sgt_bhh; pa.bhh[3] = sgc_bhh;
    pa.whhbf = whhbf; pa.gcnWbf = gcnWbf; pa.embbf = embbf;
    pa.wihbf[0] = wihbf[0]; pa.wihbf[1] = wihbf[1];
    pa.wihbf[2] = wihbf[2]; pa.wihbf[3] = wihbf[3];
    pa.biasC = biasC;
    prep_k<<<(int)((PR4 + 255) / 256), 256, 0, stream>>>(pa);
  }

  // ---- projections (K padded to 320) ----
  auto proj = [&](const int* idx, __hip_bfloat16* wih, const float* bias,
                  __hip_bfloat16* gi, int Mrows, int gx) {
    BGemmArgs ga{};
    ga.A = embbf; ga.idx = idx; ga.B = wih; ga.bias = bias; ga.C = gi;
    ga.aStride = 0; ga.bStride = 768L * 320; ga.biasStride = 768;
    ga.cStride = (long)Mrows * 768; ga.zShiftA = 0;
    ga.M = Mrows; ga.N = 768; ga.Kreal = 320; ga.lda = 320; ga.ldb = 320; ga.ldc = 768;
    bgemm_k<true, 1><<<dim3(gx, 6, 2), 256, 0, stream>>>(ga);
  };
  proj(task_target,   wihbf[0], biasC,        gi_tt, 6400, 50);
  proj(task_claim,    wihbf[1], biasC + 1536, gi_tc, 25600, 200);
  proj(shared_target, wihbf[2], biasC + 3072, gi_st, 6400, 50);
  proj(shared_claim,  wihbf[3], biasC + 4608, gi_sc, 25600, 200);

  // ---- all 8 GRU chains in ONE dispatch ----
  RecArgs ra;
  ra.whhbf = whhbf;
  ra.gi[0] = gi_tt; ra.gi[1] = gi_tc; ra.gi[2] = gi_st; ra.gi[3] = gi_sc;
  ra.bhh[0] = tgt_bhh; ra.bhh[1] = tgc_bhh; ra.bhh[2] = sgt_bhh; ra.bhh[3] = sgc_bhh;
  ra.nodebf = nodebf;
  gru_rec_k<<<dim3(8, 1, 8), 512, 0, stream>>>(ra);

  // ---- stance attention, both sides ----
  attn_k<<<dim3(128, 2), 256, 0, stream>>>(nodebf, wT, wS);

  // ---- GCN 2 layers, both sides fused; corr+softmax in one kernel ----
  for (int layer = 0; layer < 2; ++layer) {
    const __hip_bfloat16* inbf = layer ? tmpbf : nodebf;
    CsmArgs cs{inbf, corrbf};
    csm_k<<<dim3(4, 1, 256), 256, 0, stream>>>(cs);
    BGemmArgs ta{};   // trans^T = W[side] @ in^T (bf16, 0-pad cols 250..255)
    ta.A = gcnWbf + (long)layer * 262144; ta.B = inbf; ta.C = transT;
    ta.aStride = 524288; ta.bStride = 128000; ta.cStride = 131072; ta.zShiftA = 7;
    ta.M = 512; ta.N = 250; ta.Kreal = 512; ta.lda = 512; ta.ldb = 512; ta.ldc = 256;
    bgemm_k<false, 3><<<dim3(4, 2, 256), 256, 0, stream>>>(ta);
    BGemmArgs aa{};   // out = relu(res + corr @ trans), all bf16
    aa.A = corrbf; aa.B = transT; aa.Res = inbf;
    aa.C = layer ? (void*)nodebf : (void*)tmpbf;
    aa.aStride = 64000; aa.bStride = 131072; aa.cStride = 128000;
    aa.rStride = 128000; aa.zShiftA = 0;
    aa.M = 250; aa.N = 512; aa.Kreal = 256; aa.lda = 256; aa.ldb = 256; aa.ldc = 512;
    bgemm_k<false, 5><<<dim3(2, 4, 256), 256, 0, stream>>>(aa);
  }

  // ---- pooling, final linear ----
  rep_k<<<dim3(128, 2), 256, 0, stream>>>(nodebf, wT, wS, rep);
  final_k<<<dim3(128), 256, 0, stream>>>(rep, linW, linb, out);
}

// Round 16
// 1367.421 us; speedup vs baseline: 1.3815x; 1.1052x over previous
//
#include <hip/hip_runtime.h>
#include <hip/hip_bf16.h>

namespace {

constexpr int B_  = 128;
constexpr int TL  = 50, CL = 200, NNODE = 250;
constexpr int H_  = 256, D_ = 512;
constexpr long NODE_ELE = 128L * 250 * 512;   // per side

typedef __attribute__((ext_vector_type(8))) short bf16x8;
typedef __attribute__((ext_vector_type(4))) float f32x4;

__device__ inline float bits2f(unsigned v) { union { unsigned u; float f; } c; c.u = v; return c.f; }
__device__ inline unsigned f2bits(float x) { union { float f; unsigned u; } c; c.f = x; return c.u; }
__device__ inline unsigned short bfbits(float x) {
  __hip_bfloat16 b = __float2bfloat16(x);
  return *(unsigned short*)&b;
}
__device__ inline float bfsel(uint2 v, int r) {        // r-th bf16 of a 4-pack
  unsigned w = (r < 2) ? v.x : v.y;
  return bits2f((r & 1) ? (w & 0xFFFF0000u) : (w << 16));
}
__device__ inline float sigf(float x)  { return 1.f / (1.f + __expf(-x)); }
__device__ inline float tanhf_(float x){ return 1.f - 2.f / (__expf(2.f * x) + 1.f); }
__device__ inline void gld16(const __hip_bfloat16* src, char* dst) {
  __builtin_amdgcn_global_load_lds(
      (const __attribute__((address_space(1))) unsigned*)src,
      (__attribute__((address_space(3))) unsigned*)dst, 16, 0, 0);
}

// =============== bf16 MFMA GEMM (agg only): C[z]=A[z]@B[z]^T, +Res relu bf16 ==
struct BGemmArgs {
  const __hip_bfloat16* A; const __hip_bfloat16* B; const __hip_bfloat16* Res;
  void* C;
  long aStride, bStride, cStride, rStride;
  int M, N, Kreal, lda, ldb, ldc;
};

__global__ __launch_bounds__(256) void bgemm_k(BGemmArgs g) {
  __shared__ __align__(16) char As[2][16384];
  __shared__ __align__(16) char Bs[2][16384];
  const int z = blockIdx.z;
  const int m0 = blockIdx.x * 128, n0 = blockIdx.y * 128;
  const int tid = threadIdx.x;
  const int lane = tid & 63, wv = tid >> 6;
  const int wr = wv >> 1, wc = wv & 1;
  const __hip_bfloat16* Ab = g.A + (long)z * g.aStride;
  const __hip_bfloat16* Bb = g.B + (long)z * g.bStride;

  long asrc[4], bsrc[4];
  int ldso[4];
  #pragma unroll
  for (int c2 = 0; c2 < 4; ++c2) {
    int o = c2 * 256 + tid;
    int row = o >> 3, ko = o & 7;
    int colel = 8 * (ko ^ (row & 7));
    asrc[c2] = (long)(m0 + row) * g.lda + colel;
    bsrc[c2] = (long)(n0 + row) * g.ldb + colel;
    ldso[c2] = o * 16;
  }

  f32x4 acc[4][4];
  #pragma unroll
  for (int i = 0; i < 4; ++i)
    #pragma unroll
    for (int j = 0; j < 4; ++j) acc[i][j] = (f32x4){0.f, 0.f, 0.f, 0.f};

  const int KT = g.Kreal >> 6;
  #pragma unroll
  for (int c2 = 0; c2 < 4; ++c2) {
    gld16(Ab + asrc[c2], &As[0][0] + ldso[c2]);
    gld16(Bb + bsrc[c2], &Bs[0][0] + ldso[c2]);
  }
  __syncthreads();

  int buf = 0;
  for (int kt = 0; kt < KT; ++kt) {
    if (kt + 1 < KT) {
      long ko = (long)(kt + 1) * 64;
      #pragma unroll
      for (int c2 = 0; c2 < 4; ++c2) {
        gld16(Ab + asrc[c2] + ko, &As[buf ^ 1][0] + ldso[c2]);
        gld16(Bb + bsrc[c2] + ko, &Bs[buf ^ 1][0] + ldso[c2]);
      }
    }
    const char* ab = &As[buf][0];
    const char* bb = &Bs[buf][0];
    #pragma unroll
    for (int ks = 0; ks < 2; ++ks) {
      bf16x8 af[4], bfr[4];
      #pragma unroll
      for (int i = 0; i < 4; ++i) {
        int ra = wr * 64 + i * 16 + (lane & 15);
        af[i] = *(const bf16x8*)(ab + ((ra * 128 + ks * 64 + (lane >> 4) * 16) ^ ((ra & 7) << 4)));
        int rb = wc * 64 + i * 16 + (lane & 15);
        bfr[i] = *(const bf16x8*)(bb + ((rb * 128 + ks * 64 + (lane >> 4) * 16) ^ ((rb & 7) << 4)));
      }
      #pragma unroll
      for (int i = 0; i < 4; ++i)
        #pragma unroll
        for (int j = 0; j < 4; ++j)
          acc[i][j] = __builtin_amdgcn_mfma_f32_16x16x32_bf16(af[i], bfr[j], acc[i][j], 0, 0, 0);
    }
    __syncthreads();
    buf ^= 1;
  }

  const long cz = (long)z * g.cStride;
  #pragma unroll
  for (int i = 0; i < 4; ++i) {
    int rbase = m0 + wr * 64 + i * 16 + ((lane >> 4) << 2);
    #pragma unroll
    for (int j = 0; j < 4; ++j) {
      int col = n0 + wc * 64 + j * 16 + (lane & 15);
      #pragma unroll
      for (int r = 0; r < 4; ++r) {
        int row = rbase + r;
        if (row < g.M && col < g.N) {
          float v = acc[i][j][r];
          v += __bfloat162float(g.Res[(long)z * g.rStride + (long)row * g.ldc + col]);
          v = fmaxf(v, 0.f);
          ((__hip_bfloat16*)g.C)[cz + (long)row * g.ldc + col] = __float2bfloat16(v);
        }
      }
    }
  }
}

// =============== fused 4-way projection: gi = emb[tok] @ Wih^T + biasC =======
// grid (200, 6, 8): z = pj*2+dir; target projections (pj even) early-exit at
// m0 >= 6400. K = 320 (padded), N = 768, bf16 out.
struct ProjArgs {
  const __hip_bfloat16* embbf;
  const __hip_bfloat16* wih[4];
  const int* tok[4];
  const float* biasC;             // [4][2][768]
  __hip_bfloat16* gi[4];
};

__global__ __launch_bounds__(256) void proj_k(ProjArgs g) {
  __shared__ __align__(16) char As[2][16384];
  __shared__ __align__(16) char Bs[2][16384];
  const int z = blockIdx.z;
  const int pj = z >> 1, dir = z & 1;
  const int M = (pj & 1) ? 25600 : 6400;
  const int m0 = blockIdx.x * 128;
  if (m0 >= M) return;
  const int n0 = blockIdx.y * 128;
  const int tid = threadIdx.x;
  const int lane = tid & 63, wv = tid >> 6;
  const int wr = wv >> 1, wc = wv & 1;
  const __hip_bfloat16* Ab = g.embbf;
  const __hip_bfloat16* Bb = g.wih[pj] + (long)dir * 768 * 320;
  const int* idx = g.tok[pj];
  const float* bias = g.biasC + pj * 1536 + dir * 768;
  __hip_bfloat16* C = g.gi[pj] + (long)dir * M * 768;

  long asrc[4], bsrc[4];
  int ldso[4];
  #pragma unroll
  for (int c2 = 0; c2 < 4; ++c2) {
    int o = c2 * 256 + tid;
    int row = o >> 3, ko = o & 7;
    int colel = 8 * (ko ^ (row & 7));
    asrc[c2] = (long)idx[m0 + row] * 320 + colel;
    bsrc[c2] = (long)(n0 + row) * 320 + colel;
    ldso[c2] = o * 16;
  }

  f32x4 acc[4][4];
  #pragma unroll
  for (int i = 0; i < 4; ++i)
    #pragma unroll
    for (int j = 0; j < 4; ++j) acc[i][j] = (f32x4){0.f, 0.f, 0.f, 0.f};

  #pragma unroll
  for (int c2 = 0; c2 < 4; ++c2) {
    gld16(Ab + asrc[c2], &As[0][0] + ldso[c2]);
    gld16(Bb + bsrc[c2], &Bs[0][0] + ldso[c2]);
  }
  __syncthreads();

  int buf = 0;
  for (int kt = 0; kt < 5; ++kt) {
    if (kt + 1 < 5) {
      long ko = (long)(kt + 1) * 64;
      #pragma unroll
      for (int c2 = 0; c2 < 4; ++c2) {
        gld16(Ab + asrc[c2] + ko, &As[buf ^ 1][0] + ldso[c2]);
        gld16(Bb + bsrc[c2] + ko, &Bs[buf ^ 1][0] + ldso[c2]);
      }
    }
    const char* ab = &As[buf][0];
    const char* bb = &Bs[buf][0];
    #pragma unroll
    for (int ks = 0; ks < 2; ++ks) {
      bf16x8 af[4], bfr[4];
      #pragma unroll
      for (int i = 0; i < 4; ++i) {
        int ra = wr * 64 + i * 16 + (lane & 15);
        af[i] = *(const bf16x8*)(ab + ((ra * 128 + ks * 64 + (lane >> 4) * 16) ^ ((ra & 7) << 4)));
        int rb = wc * 64 + i * 16 + (lane & 15);
        bfr[i] = *(const bf16x8*)(bb + ((rb * 128 + ks * 64 + (lane >> 4) * 16) ^ ((rb & 7) << 4)));
      }
      #pragma unroll
      for (int i = 0; i < 4; ++i)
        #pragma unroll
        for (int j = 0; j < 4; ++j)
          acc[i][j] = __builtin_amdgcn_mfma_f32_16x16x32_bf16(af[i], bfr[j], acc[i][j], 0, 0, 0);
    }
    __syncthreads();
    buf ^= 1;
  }

  #pragma unroll
  for (int i = 0; i < 4; ++i) {
    int rbase = m0 + wr * 64 + i * 16 + ((lane >> 4) << 2);
    #pragma unroll
    for (int j = 0; j < 4; ++j) {
      int col = n0 + wc * 64 + j * 16 + (lane & 15);
      float bv = bias[col];
      #pragma unroll
      for (int r = 0; r < 4; ++r) {
        int row = rbase + r;
        C[(long)row * 768 + col] = __float2bfloat16(acc[i][j][r] + bv);
      }
    }
  }
}

// ====== fused GCN front: csm (corr+softmax) | trans | attn, one dispatch =====
// blocks [0,1024): csm   m = bid&3,  z = bid>>2
// blocks [1024,3072): trans x=(t)&3, y=(t>>2)&1, z=t>>3
// blocks [3072,3328): attn (layer 0 only)
struct GfuArgs {
  const __hip_bfloat16* inbf;     // [256][250][512]
  __hip_bfloat16* corrbf;         // [256][250][256]
  const __hip_bfloat16* gcnW;     // layer base: [side][512][512] (stride 524288)
  __hip_bfloat16* transT;         // [256][512][256]
  const __hip_bfloat16* nodebf;
  float *wT, *wS;
};

__device__ void csm_body(char* lds, const __hip_bfloat16* in, __hip_bfloat16* outp,
                         int mblk, int z) {
  char* As = lds;                 // [2][8192]
  char* Bs = lds + 16384;         // [2][32768]
  const int m0 = mblk * 64;
  const int tid = threadIdx.x;
  const int lane = tid & 63, wv = tid >> 6;
  const __hip_bfloat16* base = in + (long)z * 128000;

  long bsrc[8]; int bo[8];
  #pragma unroll
  for (int c2 = 0; c2 < 8; ++c2) {
    int o = c2 * 256 + tid;
    int row = o >> 3, ko = o & 7;
    bsrc[c2] = (long)row * 512 + 8 * (ko ^ (row & 7));
    bo[c2] = o * 16;
  }
  long asrc[2]; int ao[2];
  #pragma unroll
  for (int c2 = 0; c2 < 2; ++c2) {
    int o = c2 * 256 + tid;
    int row = o >> 3, ko = o & 7;
    asrc[c2] = (long)(m0 + row) * 512 + 8 * (ko ^ (row & 7));
    ao[c2] = o * 16;
  }

  f32x4 acc[16];
  #pragma unroll
  for (int j = 0; j < 16; ++j) acc[j] = (f32x4){0.f, 0.f, 0.f, 0.f};

  #pragma unroll
  for (int c2 = 0; c2 < 2; ++c2) gld16(base + asrc[c2], As + ao[c2]);
  #pragma unroll
  for (int c2 = 0; c2 < 8; ++c2) gld16(base + bsrc[c2], Bs + bo[c2]);
  __syncthreads();

  int buf = 0;
  for (int kt = 0; kt < 8; ++kt) {
    if (kt + 1 < 8) {
      long ko = (long)(kt + 1) * 64;
      #pragma unroll
      for (int c2 = 0; c2 < 2; ++c2) gld16(base + asrc[c2] + ko, As + (buf ^ 1) * 8192 + ao[c2]);
      #pragma unroll
      for (int c2 = 0; c2 < 8; ++c2) gld16(base + bsrc[c2] + ko, Bs + (buf ^ 1) * 32768 + bo[c2]);
    }
    const char* ab = As + buf * 8192;
    const char* bb = Bs + buf * 32768;
    #pragma unroll
    for (int ks = 0; ks < 2; ++ks) {
      int ra = wv * 16 + (lane & 15);
      bf16x8 af = *(const bf16x8*)(ab + ((ra * 128 + ks * 64 + (lane >> 4) * 16) ^ ((ra & 7) << 4)));
      #pragma unroll
      for (int j = 0; j < 16; ++j) {
        int rb = j * 16 + (lane & 15);
        bf16x8 bf = *(const bf16x8*)(bb + ((rb * 128 + ks * 64 + (lane >> 4) * 16) ^ ((rb & 7) << 4)));
        acc[j] = __builtin_amdgcn_mfma_f32_16x16x32_bf16(af, bf, acc[j], 0, 0, 0);
      }
    }
    __syncthreads();
    buf ^= 1;
  }

  const int c0 = lane & 15, rq = lane >> 4;
  const long obase = (long)z * 64000;
  #pragma unroll
  for (int r = 0; r < 4; ++r) {
    int row = m0 + wv * 16 + rq * 4 + r;
    float vals[16];
    float mx = -1e30f;
    #pragma unroll
    for (int j = 0; j < 16; ++j) {
      vals[j] = acc[j][r];
      if (j * 16 + c0 < 250) mx = fmaxf(mx, vals[j]);
    }
    #pragma unroll
    for (int o = 1; o < 16; o <<= 1) mx = fmaxf(mx, __shfl_xor(mx, o, 64));
    float s = 0.f;
    #pragma unroll
    for (int j = 0; j < 16; ++j) {
      float e = (j * 16 + c0 < 250) ? __expf(vals[j] - mx) : 0.f;
      vals[j] = e; s += e;
    }
    #pragma unroll
    for (int o = 1; o < 16; o <<= 1) s += __shfl_xor(s, o, 64);
    float inv = 1.f / s;
    if (row < 250) {
      #pragma unroll
      for (int j = 0; j < 16; ++j)
        outp[obase + (long)row * 256 + j * 16 + c0] = __float2bfloat16(vals[j] * inv);
    }
  }
}

__device__ void trans_body(char* lds, const __hip_bfloat16* W,
                           const __hip_bfloat16* in, __hip_bfloat16* transT,
                           int xb, int yb, int z) {
  char* As = lds;                 // [2][16384]
  char* Bs = lds + 32768;         // [2][16384]
  const int m0 = xb * 128, n0 = yb * 128;
  const int tid = threadIdx.x;
  const int lane = tid & 63, wv = tid >> 6;
  const int wr = wv >> 1, wc = wv & 1;
  const __hip_bfloat16* Ab = W + (long)(z >> 7) * 524288;
  const __hip_bfloat16* Bb = in + (long)z * 128000;

  long asrc[4], bsrc[4];
  int ldso[4];
  #pragma unroll
  for (int c2 = 0; c2 < 4; ++c2) {
    int o = c2 * 256 + tid;
    int row = o >> 3, ko = o & 7;
    int colel = 8 * (ko ^ (row & 7));
    asrc[c2] = (long)(m0 + row) * 512 + colel;
    bsrc[c2] = (long)(n0 + row) * 512 + colel;
    ldso[c2] = o * 16;
  }

  f32x4 acc[4][4];
  #pragma unroll
  for (int i = 0; i < 4; ++i)
    #pragma unroll
    for (int j = 0; j < 4; ++j) acc[i][j] = (f32x4){0.f, 0.f, 0.f, 0.f};

  #pragma unroll
  for (int c2 = 0; c2 < 4; ++c2) {
    gld16(Ab + asrc[c2], As + ldso[c2]);
    gld16(Bb + bsrc[c2], Bs + ldso[c2]);
  }
  __syncthreads();

  int buf = 0;
  for (int kt = 0; kt < 8; ++kt) {
    if (kt + 1 < 8) {
      long ko = (long)(kt + 1) * 64;
      #pragma unroll
      for (int c2 = 0; c2 < 4; ++c2) {
        gld16(Ab + asrc[c2] + ko, As + (buf ^ 1) * 16384 + ldso[c2]);
        gld16(Bb + bsrc[c2] + ko, Bs + (buf ^ 1) * 16384 + ldso[c2]);
      }
    }
    const char* ab = As + buf * 16384;
    const char* bb = Bs + buf * 16384;
    #pragma unroll
    for (int ks = 0; ks < 2; ++ks) {
      bf16x8 af[4], bfr[4];
      #pragma unroll
      for (int i = 0; i < 4; ++i) {
        int ra = wr * 64 + i * 16 + (lane & 15);
        af[i] = *(const bf16x8*)(ab + ((ra * 128 + ks * 64 + (lane >> 4) * 16) ^ ((ra & 7) << 4)));
        int rb = wc * 64 + i * 16 + (lane & 15);
        bfr[i] = *(const bf16x8*)(bb + ((rb * 128 + ks * 64 + (lane >> 4) * 16) ^ ((rb & 7) << 4)));
      }
      #pragma unroll
      for (int i = 0; i < 4; ++i)
        #pragma unroll
        for (int j = 0; j < 4; ++j)
          acc[i][j] = __builtin_amdgcn_mfma_f32_16x16x32_bf16(af[i], bfr[j], acc[i][j], 0, 0, 0);
    }
    __syncthreads();
    buf ^= 1;
  }

  const long cz = (long)z * 131072;
  #pragma unroll
  for (int i = 0; i < 4; ++i) {
    int rbase = m0 + wr * 64 + i * 16 + ((lane >> 4) << 2);
    #pragma unroll
    for (int j = 0; j < 4; ++j) {
      int col = n0 + wc * 64 + j * 16 + (lane & 15);
      if (col < 256) {
        #pragma unroll
        for (int r = 0; r < 4; ++r) {
          int row = rbase + r;
          transT[cz + (long)row * 256 + col] =
              __float2bfloat16(col < 250 ? acc[i][j][r] : 0.f);
        }
      }
    }
  }
}

__device__ void attn_body(char* lds, const __hip_bfloat16* nodeAll,
                          float* wT, float* wS, int b, int side) {
  float* tl = (float*)lds;          // [512]
  float* sc = (float*)(lds + 2048); // [200]
  const __hip_bfloat16* node = nodeAll + (long)side * NODE_ELE;
  float* w = side ? wS : wT;
  int tid = threadIdx.x;
  {
    const __hip_bfloat16* tr = node + ((long)b * NNODE + (TL - 1)) * D_;
    tl[tid]       = __bfloat162float(tr[tid]);
    tl[tid + 256] = __bfloat162float(tr[tid + 256]);
  }
  __syncthreads();
  int wid = tid >> 6, lane = tid & 63;
  for (int c = wid; c < CL; c += 4) {
    const __hip_bfloat16* row = node + ((long)b * NNODE + TL + c) * D_;
    uint4 v = *(const uint4*)(row + lane * 8);
    const float* tp = &tl[lane * 8];
    float acc = bits2f(v.x << 16)         * tp[0] + bits2f(v.x & 0xFFFF0000u) * tp[1]
              + bits2f(v.y << 16)         * tp[2] + bits2f(v.y & 0xFFFF0000u) * tp[3]
              + bits2f(v.z << 16)         * tp[4] + bits2f(v.z & 0xFFFF0000u) * tp[5]
              + bits2f(v.w << 16)         * tp[6] + bits2f(v.w & 0xFFFF0000u) * tp[7];
    #pragma unroll
    for (int o = 32; o; o >>= 1) acc += __shfl_xor(acc, o, 64);
    if (lane == 0) sc[c] = acc;
  }
  __syncthreads();
  if (wid == 0) {
    float v[4]; float m = -1e30f;
    #pragma unroll
    for (int i = 0; i < 4; ++i) {
      int c = lane + 64 * i;
      v[i] = (c < CL) ? sc[c] : -1e30f;
      m = fmaxf(m, v[i]);
    }
    #pragma unroll
    for (int o = 32; o; o >>= 1) m = fmaxf(m, __shfl_xor(m, o, 64));
    float s = 0.f;
    #pragma unroll
    for (int i = 0; i < 4; ++i) {
      int c = lane + 64 * i;
      v[i] = (c < CL) ? expf(v[i] - m) : 0.f;
      s += v[i];
    }
    #pragma unroll
    for (int o = 32; o; o >>= 1) s += __shfl_xor(s, o, 64);
    float inv = 1.f / s;
    #pragma unroll
    for (int i = 0; i < 4; ++i) {
      int c = lane + 64 * i;
      if (c < CL) w[(long)b * CL + c] = v[i] * inv;
    }
  }
}

__global__ __launch_bounds__(256) void gfu_k(GfuArgs g) {
  __shared__ __align__(16) char lds[81920];
  const int bid = blockIdx.x;
  if (bid < 1024) {
    csm_body(lds, g.inbf, g.corrbf, bid & 3, bid >> 2);
  } else if (bid < 3072) {
    int t = bid - 1024;
    trans_body(lds, g.gcnW, g.inbf, g.transT, t & 3, (t >> 2) & 1, t >> 3);
  } else {
    int t = bid - 3072;
    attn_body(lds, g.nodebf, g.wT, g.wS, t & 127, t >> 7);
  }
}

// ---------------- fused prep: whh/gcnW/emb/wih -> bf16(+pad 320), biasC -------
struct PrepArgs {
  const float* whh[4];
  const float* gcnW[2];
  const float* emb;
  const float* wih[4];
  const float* bih[4];
  const float* bhh[4];
  __hip_bfloat16 *whhbf, *gcnWbf, *embbf;
  __hip_bfloat16* wihbf[4];
  float* biasC;
};

constexpr long PR0 = 1572864;
constexpr long PR1 = PR0 + 1048576;
constexpr long PR2 = PR1 + 9600000;
constexpr long PR3 = PR2 + 1966080;
constexpr long PR4 = PR3 + 6144;

__global__ __launch_bounds__(256) void prep_k(PrepArgs a) {
  long i = (long)blockIdx.x * 256 + threadIdx.x;
  if (i >= PR4) return;
  if (i < PR0) {
    int zz = (int)(i / 196608);
    long rem = i - (long)zz * 196608;
    a.whhbf[i] = __float2bfloat16(a.whh[zz >> 1][(long)(zz & 1) * 196608 + rem]);
  } else if (i < PR1) {
    long j = i - PR0;
    a.gcnWbf[j] = __float2bfloat16(a.gcnW[j / 524288][j % 524288]);
  } else if (i < PR2) {
    long j = i - PR1;
    long r = j / 320;
    int c = (int)(j - r * 320);
    a.embbf[j] = __float2bfloat16(c < 300 ? a.emb[r * 300 + c] : 0.f);
  } else if (i < PR3) {
    long j = i - PR2;
    int w = (int)(j / 491520);
    long k = j - (long)w * 491520;
    long r = k / 320;
    int c = (int)(k - r * 320);
    a.wihbf[w][k] = __float2bfloat16(c < 300 ? a.wih[w][r * 300 + c] : 0.f);
  } else {
    long j = i - PR3;
    int w = (int)(j / 1536);
    int k = (int)(j - (long)w * 1536);
    a.biasC[(long)w * 1536 + k] = a.bih[w][k] + ((k % 768) < 512 ? a.bhh[w][k] : 0.f);
  }
}

// ---------------- GRU recurrence (R13 structure, measured floor ~802us) ------
struct RecArgs {
  const __hip_bfloat16* whhbf;
  const __hip_bfloat16* gi[4];
  const float* bhh[4];
  __hip_bfloat16* nodebf;
};

__global__ __launch_bounds__(512, 2) void gru_rec_k(RecArgs a) {
  __shared__ __align__(16) char hbuf[2][8192];
  const int z = blockIdx.z;
  const int side = z >> 2, sq = (z >> 1) & 1, dir = z & 1;
  const int gidx = side * 2 + sq;
  const int T = sq ? CL : TL;
  const int toff = sq ? TL : 0;
  const __hip_bfloat16* gi = a.gi[gidx] + (long)dir * B_ * T * 768;
  const float* bhh = a.bhh[gidx] + dir * 768;
  const __hip_bfloat16* whh = a.whhbf + (long)z * 768 * 256;
  __hip_bfloat16* nodeb = a.nodebf + (long)side * NODE_ELE;
  const int b0 = blockIdx.x * 16;
  const int tid = threadIdx.x;
  const int lane = tid & 63, wv = tid >> 6;
  const int bcol = lane & 15, g4 = lane >> 4;
  const int u0 = wv * 32 + g4 * 4;
  const int swzh = (bcol & 15) << 4;

  bf16x8 Af[3][2][8];
  #pragma unroll
  for (int g = 0; g < 3; ++g)
    #pragma unroll
    for (int h = 0; h < 2; ++h)
      #pragma unroll
      for (int kt = 0; kt < 8; ++kt) {
        int row = g * 256 + wv * 32 + h * 16 + bcol;
        int col = kt * 32 + g4 * 8;
        Af[g][h][kt] = *(const bf16x8*)(whh + (long)row * 256 + col);
      }
  *(uint4*)&hbuf[0][tid * 16] = make_uint4(0, 0, 0, 0);
  const float4 bn0 = *(const float4*)&bhh[512 + u0];
  const float4 bn1 = *(const float4*)&bhh[512 + u0 + 16];
  __syncthreads();

  const __hip_bfloat16* gip = gi + ((long)(b0 + bcol) * T + (dir ? T - 1 : 0)) * 768 + u0;
  __hip_bfloat16* np = nodeb + ((long)(b0 + bcol) * NNODE + toff + (dir ? T - 1 : 0)) * D_
                       + dir * H_ + u0;
  const long gistep = dir ? -768L : 768L;
  const long nstep  = dir ? -(long)D_ : (long)D_;
  int cur = 0;

  float hreg[2][4];
  #pragma unroll
  for (int h = 0; h < 2; ++h)
    #pragma unroll
    for (int r = 0; r < 4; ++r) hreg[h][r] = 0.f;

  uint2 gv[3][2];
  #pragma unroll
  for (int g = 0; g < 3; ++g)
    #pragma unroll
    for (int h = 0; h < 2; ++h)
      gv[g][h] = *(const uint2*)(gip + g * 256 + h * 16);

  for (int t = 0; t < T; ++t) {
    const char* hib = &hbuf[cur][0];
    f32x4 c[3][2];
    #pragma unroll
    for (int g = 0; g < 3; ++g)
      #pragma unroll
      for (int h = 0; h < 2; ++h) c[g][h] = (f32x4){0.f, 0.f, 0.f, 0.f};
    const int rb = bcol * 512 + g4 * 16;
    #pragma unroll
    for (int kt = 0; kt < 8; ++kt) {
      bf16x8 bh = *(const bf16x8*)(hib + ((rb + kt * 64) ^ swzh));
      #pragma unroll
      for (int g = 0; g < 3; ++g)
        #pragma unroll
        for (int h = 0; h < 2; ++h)
          c[g][h] = __builtin_amdgcn_mfma_f32_16x16x32_bf16(Af[g][h][kt], bh, c[g][h], 0, 0, 0);
    }

    #pragma unroll
    for (int h = 0; h < 2; ++h) {
      float4 bn = h ? bn1 : bn0;
      #pragma unroll
      for (int r = 0; r < 4; ++r) {
        float bnv = (r == 0) ? bn.x : (r == 1) ? bn.y : (r == 2) ? bn.z : bn.w;
        float rr = sigf(bfsel(gv[0][h], r) + c[0][h][r]);
        float zz = sigf(bfsel(gv[1][h], r) + c[1][h][r]);
        float nn = tanhf_(bfsel(gv[2][h], r) + rr * (c[2][h][r] + bnv));
        hreg[h][r] = (1.f - zz) * nn + zz * hreg[h][r];
      }
    }

    {
      const __hip_bfloat16* gn = (t + 1 < T) ? gip + gistep : gip;
      gip = gn;
      #pragma unroll
      for (int g = 0; g < 3; ++g)
        #pragma unroll
        for (int h = 0; h < 2; ++h)
          gv[g][h] = *(const uint2*)(gn + g * 256 + h * 16);
    }

    const int ob0 = bcol * 512 + u0 * 2;
    char* hibn = &hbuf[cur ^ 1][0];
    #pragma unroll
    for (int h = 0; h < 2; ++h) {
      unsigned hb[4];
      #pragma unroll
      for (int r = 0; r < 4; ++r)
        hb[r] = (f2bits(hreg[h][r]) + 0x8000u) & 0xFFFF0000u;
      uint2 hiw;
      hiw.x = (hb[0] >> 16) | hb[1];
      hiw.y = (hb[2] >> 16) | hb[3];
      *(uint2*)(np + h * 16) = hiw;
      *(uint2*)(hibn + ((ob0 + h * 32) ^ swzh)) = hiw;
    }
    np += nstep;
    asm volatile("s_waitcnt lgkmcnt(0)" ::: "memory");
    __builtin_amdgcn_sched_barrier(0);
    __builtin_amdgcn_s_barrier();
    cur ^= 1;
  }
}

// ---------------- weighted claim pooling (bf16 node, both sides) ----------------
__global__ __launch_bounds__(256) void rep_k(const __hip_bfloat16* nodeAll,
                                             const float* wT, const float* wS,
                                             float* rep) {
  int b = blockIdx.x, side = blockIdx.y;
  const __hip_bfloat16* node = nodeAll + (long)side * NODE_ELE;
  const float* w = side ? wS : wT;
  __shared__ float wl[CL];
  int tid = threadIdx.x;
  if (tid < CL) wl[tid] = w[(long)b * CL + tid];
  __syncthreads();
  #pragma unroll
  for (int h = 0; h < 2; ++h) {
    int d = tid + h * 256;
    float acc = 0.f;
    for (int c = 0; c < CL; ++c)
      acc = fmaf(wl[c], __bfloat162float(node[((long)b * NNODE + TL + c) * D_ + d]), acc);
    rep[((long)side * B_ + b) * D_ + d] = acc;
  }
}

// ---------------- final linear ----------------
__global__ __launch_bounds__(256) void final_k(const float* rep, const float* linW,
                                               const float* linb, float* out) {
  int b = blockIdx.x, tid = threadIdx.x;
  float a0 = 0.f, a1 = 0.f, a2 = 0.f;
  for (int d = tid; d < 1024; d += 256) {
    float x = rep[(long)(d >> 9) * (B_ * D_) + (long)b * D_ + (d & 511)];
    a0 = fmaf(x, linW[d], a0);
    a1 = fmaf(x, linW[1024 + d], a1);
    a2 = fmaf(x, linW[2048 + d], a2);
  }
  #pragma unroll
  for (int o = 32; o; o >>= 1) {
    a0 += __shfl_xor(a0, o, 64);
    a1 += __shfl_xor(a1, o, 64);
    a2 += __shfl_xor(a2, o, 64);
  }
  __shared__ float red[3][4];
  int wid = tid >> 6, lane = tid & 63;
  if (lane == 0) { red[0][wid] = a0; red[1][wid] = a1; red[2][wid] = a2; }
  __syncthreads();
  if (tid == 0) {
    out[b * 3 + 0] = red[0][0] + red[0][1] + red[0][2] + red[0][3] + linb[0];
    out[b * 3 + 1] = red[1][0] + red[1][1] + red[1][2] + red[1][3] + linb[1];
    out[b * 3 + 2] = red[2][0] + red[2][1] + red[2][2] + red[2][3] + linb[2];
  }
}

// ---------------- diagnostic ----------------
__global__ void diag_k(float* out, int n, float v) {
  int i = blockIdx.x * blockDim.x + threadIdx.x;
  if (i < n) out[i] = v;
}

} // namespace

extern "C" void kernel_launch(void* const* d_in, const int* in_sizes, int n_in,
                              void* d_out, int out_size, void* d_ws, size_t ws_size,
                              hipStream_t stream) {
  const int* task_target   = (const int*)d_in[1];
  const int* shared_target = (const int*)d_in[2];
  const int* task_claim    = (const int*)d_in[3];
  const int* shared_claim  = (const int*)d_in[4];
  const float* emb      = (const float*)d_in[9];
  const float* tgt_wih  = (const float*)d_in[10];
  const float* tgt_whh  = (const float*)d_in[11];
  const float* tgt_bih  = (const float*)d_in[12];
  const float* tgt_bhh  = (const float*)d_in[13];
  const float* tgc_wih  = (const float*)d_in[14];
  const float* tgc_whh  = (const float*)d_in[15];
  const float* tgc_bih  = (const float*)d_in[16];
  const float* tgc_bhh  = (const float*)d_in[17];
  const float* sgt_wih  = (const float*)d_in[18];
  const float* sgt_whh  = (const float*)d_in[19];
  const float* sgt_bih  = (const float*)d_in[20];
  const float* sgt_bhh  = (const float*)d_in[21];
  const float* sgc_wih  = (const float*)d_in[22];
  const float* sgc_whh  = (const float*)d_in[23];
  const float* sgc_bih  = (const float*)d_in[24];
  const float* sgc_bhh  = (const float*)d_in[25];
  const float* gcnW_task   = (const float*)d_in[26];
  const float* gcnW_shared = (const float*)d_in[27];
  const float* linW = (const float*)d_in[28];
  const float* linb = (const float*)d_in[29];
  float* out = (float*)d_out;

  const size_t SZ_WHH   = 3145728;
  const size_t SZ_GCNW  = 2097152;
  const size_t SZ_BIASC = 24576;
  const size_t SZ_ARENA = 196608000;
  const size_t SZ_NODE  = 65536000;
  const size_t SZ_W     = 102400;
  const size_t SZ_REP   = 524288;
  const size_t NEED = SZ_WHH + SZ_GCNW + SZ_BIASC + SZ_ARENA + SZ_NODE
                      + 2 * SZ_W + SZ_REP + 4096;

  if (ws_size < NEED) {
    diag_k<<<(out_size + 255) / 256, 256, 0, stream>>>(out, out_size,
                                                       (float)(ws_size >> 20));
    return;
  }

  char* p = (char*)d_ws;
  auto alloc = [&](size_t bytes) { char* r = p; p += (bytes + 255) & ~(size_t)255; return r; };
  __hip_bfloat16* whhbf  = (__hip_bfloat16*)alloc(SZ_WHH);
  __hip_bfloat16* gcnWbf = (__hip_bfloat16*)alloc(SZ_GCNW);
  float* biasC = (float*)alloc(SZ_BIASC);
  char* arena  = alloc(SZ_ARENA);
  char* nodeC  = alloc(SZ_NODE);
  float* wT    = (float*)alloc(SZ_W);
  float* wS    = (float*)alloc(SZ_W);
  float* rep   = (float*)alloc(SZ_REP);
  __hip_bfloat16* nodebf = (__hip_bfloat16*)nodeC;

  // phase-A views
  __hip_bfloat16* gi_tt = (__hip_bfloat16*)(arena);
  __hip_bfloat16* gi_tc = (__hip_bfloat16*)(arena + 19660800);
  __hip_bfloat16* gi_st = (__hip_bfloat16*)(arena + 98304000);
  __hip_bfloat16* gi_sc = (__hip_bfloat16*)(arena + 117964800);
  __hip_bfloat16* embbf = (__hip_bfloat16*)(nodeC);                  // [30000][320]
  __hip_bfloat16* wihbf[4] = {
    (__hip_bfloat16*)(nodeC + 19200000),
    (__hip_bfloat16*)(nodeC + 20183040),
    (__hip_bfloat16*)(nodeC + 21166080),
    (__hip_bfloat16*)(nodeC + 22149120)};
  // phase-B views
  __hip_bfloat16* tmpbf  = (__hip_bfloat16*)(arena);                 // [256][250][512]
  __hip_bfloat16* corrbf = (__hip_bfloat16*)(arena + 65536000);      // [256][250][256]
  __hip_bfloat16* transT = (__hip_bfloat16*)(arena + 98304000);      // [256][512][256]

  // ---- 1) fused prep ----
  {
    PrepArgs pa;
    pa.whh[0] = tgt_whh; pa.whh[1] = tgc_whh; pa.whh[2] = sgt_whh; pa.whh[3] = sgc_whh;
    pa.gcnW[0] = gcnW_task; pa.gcnW[1] = gcnW_shared;
    pa.emb = emb;
    pa.wih[0] = tgt_wih; pa.wih[1] = tgc_wih; pa.wih[2] = sgt_wih; pa.wih[3] = sgc_wih;
    pa.bih[0] = tgt_bih; pa.bih[1] = tgc_bih; pa.bih[2] = sgt_bih; pa.bih[3] = sgc_bih;
    pa.bhh[0] = tgt_bhh; pa.bhh[1] = tgc_bhh; pa.bhh[2] = sgt_bhh; pa.bhh[3] = sgc_bhh;
    pa.whhbf = whhbf; pa.gcnWbf = gcnWbf; pa.embbf = embbf;
    pa.wihbf[0] = wihbf[0]; pa.wihbf[1] = wihbf[1];
    pa.wihbf[2] = wihbf[2]; pa.wihbf[3] = wihbf[3];
    pa.biasC = biasC;
    prep_k<<<(int)((PR4 + 255) / 256), 256, 0, stream>>>(pa);
  }

  // ---- 2) all 4 projections in ONE dispatch ----
  {
    ProjArgs ja;
    ja.embbf = embbf;
    ja.wih[0] = wihbf[0]; ja.wih[1] = wihbf[1]; ja.wih[2] = wihbf[2]; ja.wih[3] = wihbf[3];
    ja.tok[0] = task_target; ja.tok[1] = task_claim;
    ja.tok[2] = shared_target; ja.tok[3] = shared_claim;
    ja.biasC = biasC;
    ja.gi[0] = gi_tt; ja.gi[1] = gi_tc; ja.gi[2] = gi_st; ja.gi[3] = gi_sc;
    proj_k<<<dim3(200, 6, 8), 256, 0, stream>>>(ja);
  }

  // ---- 3) all 8 GRU chains in ONE dispatch ----
  RecArgs ra;
  ra.whhbf = whhbf;
  ra.gi[0] = gi_tt; ra.gi[1] = gi_tc; ra.gi[2] = gi_st; ra.gi[3] = gi_sc;
  ra.bhh[0] = tgt_bhh; ra.bhh[1] = tgc_bhh; ra.bhh[2] = sgt_bhh; ra.bhh[3] = sgc_bhh;
  ra.nodebf = nodebf;
  gru_rec_k<<<dim3(8, 1, 8), 512, 0, stream>>>(ra);

  // ---- 4/5) GCN layers: fused csm+trans(+attn) then agg ----
  for (int layer = 0; layer < 2; ++layer) {
    const __hip_bfloat16* inbf = layer ? tmpbf : nodebf;
    GfuArgs gf;
    gf.inbf = inbf; gf.corrbf = corrbf;
    gf.gcnW = gcnWbf + (long)layer * 262144; gf.transT = transT;
    gf.nodebf = nodebf; gf.wT = wT; gf.wS = wS;
    gfu_k<<<dim3(layer == 0 ? 3328 : 3072), 256, 0, stream>>>(gf);
    BGemmArgs aa{};   // out = relu(res + corr @ trans), all bf16
    aa.A = corrbf; aa.B = transT; aa.Res = inbf;
    aa.C = layer ? (void*)nodebf : (void*)tmpbf;
    aa.aStride = 64000; aa.bStride = 131072; aa.cStride = 128000; aa.rStride = 128000;
    aa.M = 250; aa.N = 512; aa.Kreal = 256; aa.lda = 256; aa.ldb = 256; aa.ldc = 512;
    bgemm_k<<<dim3(2, 4, 256), 256, 0, stream>>>(aa);
  }

  // ---- 6) pooling, 7) final linear ----
  rep_k<<<dim3(128, 2), 256, 0, stream>>>(nodebf, wT, wS, rep);
  final_k<<<dim3(128), 256, 0, stream>>>(rep, linW, linb, out);
}